// Round 4
// baseline (1288.420 us; speedup 1.0000x reference)
//
#include <hip/hip_runtime.h>
#include <hip/hip_bf16.h>

#define NEGS   0.2f
#define LN_EPS 1e-5f

typedef const float* __restrict__ fp;

// monotone float<->uint encoding for atomicMax on floats
__device__ __forceinline__ unsigned fenc(float f){
  unsigned b = __float_as_uint(f);
  return (b & 0x80000000u) ? ~b : (b | 0x80000000u);
}
__device__ __forceinline__ float fdec(unsigned u){
  unsigned b = (u & 0x80000000u) ? (u ^ 0x80000000u) : ~u;
  return __uint_as_float(b);
}

// ---------------- input transform: h = relu(x @ w_in + b_in) ----------------
__global__ __launch_bounds__(256) void k_in(fp x, fp w, fp b, float* __restrict__ h, int N){
  __shared__ float ws[24*64];
  __shared__ float bs[64];
  __shared__ float xs[4][24];
  int tid = threadIdx.x;
  for (int i = tid; i < 24*64; i += 256) ws[i] = w[i];
  if (tid < 64) bs[tid] = b[tid];
  int r = tid >> 6, c = tid & 63;
  int row = blockIdx.x*4 + r;
  if (c < 24 && row < N) xs[r][c] = x[row*24 + c];
  __syncthreads();
  if (row < N){
    float acc = bs[c];
    #pragma unroll
    for (int k = 0; k < 24; ++k) acc = fmaf(xs[r][k], ws[k*64 + c], acc);
    h[row*64 + c] = fmaxf(acc, 0.f);
  }
}

// ---------------- CSR build ----------------
__global__ void k_zero(int* __restrict__ p, int n){
  int i = blockIdx.x*256 + threadIdx.x;
  if (i < n) p[i] = 0;
}

__global__ void k_hist(const int* __restrict__ dst, int* __restrict__ counts, int E){
  int e = blockIdx.x*256 + threadIdx.x;
  if (e < E) atomicAdd(&counts[dst[e]], 1);
}

__global__ __launch_bounds__(256) void k_scan1(const int* __restrict__ counts, int* __restrict__ scanned,
                                               int* __restrict__ bsums, int N){
  __shared__ int s[256];
  int i = blockIdx.x*256 + threadIdx.x;
  int v = (i < N) ? counts[i] : 0;
  s[threadIdx.x] = v;
  __syncthreads();
  for (int off = 1; off < 256; off <<= 1){
    int t = (threadIdx.x >= off) ? s[threadIdx.x - off] : 0;
    __syncthreads();
    s[threadIdx.x] += t;
    __syncthreads();
  }
  if (i < N) scanned[i] = s[threadIdx.x];
  if (threadIdx.x == 255) bsums[blockIdx.x] = s[255];
}

__global__ __launch_bounds__(256) void k_scan2(int* __restrict__ bsums, int NB){
  __shared__ int s[256];
  int v = (threadIdx.x < NB) ? bsums[threadIdx.x] : 0;
  s[threadIdx.x] = v;
  __syncthreads();
  for (int off = 1; off < 256; off <<= 1){
    int t = (threadIdx.x >= off) ? s[threadIdx.x - off] : 0;
    __syncthreads();
    s[threadIdx.x] += t;
    __syncthreads();
  }
  if (threadIdx.x < NB) bsums[threadIdx.x] = s[threadIdx.x] - v;
}

__global__ void k_scan3(const int* __restrict__ scanned, const int* __restrict__ bsums,
                        int* __restrict__ row_ptr, int* __restrict__ cursor, int N){
  int i = blockIdx.x*256 + threadIdx.x;
  if (i < N){
    row_ptr[i+1] = scanned[i] + bsums[blockIdx.x];
    cursor[i] = 0;
    if (i == 0) row_ptr[0] = 0;
  }
}

__global__ void k_scatter(const int* __restrict__ srcA, const int* __restrict__ dstA,
                          const int* __restrict__ row_ptr, int* __restrict__ cursor,
                          int* __restrict__ col, int E){
  int e = blockIdx.x*256 + threadIdx.x;
  if (e < E){
    int d = dstA[e];
    int p = atomicAdd(&cursor[d], 1);
    col[row_ptr[d] + p] = srcA[e];
  }
}

// ---------------- per-layer transforms: xl = h@wl+bl, xr = h@wr+br ----------------
__global__ __launch_bounds__(256) void k_xfm(const float* __restrict__ h, fp wlg, fp blg, fp wrg, fp brg,
                                             float* __restrict__ xl, float* __restrict__ xr, int N){
  __shared__ float wl[4096];
  __shared__ float wr[4096];
  __shared__ float hs[64*64];
  int tid = threadIdx.x;
  for (int i = tid*4; i < 4096; i += 1024){
    *(float4*)&wl[i] = *(const float4*)&wlg[i];
    *(float4*)&wr[i] = *(const float4*)&wrg[i];
  }
  int row0 = blockIdx.x*64;
  int nrows = min(64, N - row0);
  int lim = nrows*64;
  for (int i = tid*4; i < lim; i += 1024)
    *(float4*)&hs[i] = *(const float4*)&h[(size_t)row0*64 + i];
  __syncthreads();
  int wave = tid >> 6, c = tid & 63;
  float blv = blg[c], brv = brg[c];
  float accl[16], accr[16];
  #pragma unroll
  for (int r = 0; r < 16; ++r){ accl[r] = blv; accr[r] = brv; }
  int rbase = wave*16;
  #pragma unroll 4
  for (int k = 0; k < 64; k += 4){
    float w0 = wl[k*64+c], w1 = wl[(k+1)*64+c], w2 = wl[(k+2)*64+c], w3 = wl[(k+3)*64+c];
    float v0 = wr[k*64+c], v1 = wr[(k+1)*64+c], v2 = wr[(k+2)*64+c], v3 = wr[(k+3)*64+c];
    #pragma unroll
    for (int r = 0; r < 16; ++r){
      float4 hv = *(const float4*)&hs[(rbase + r)*64 + k];
      accl[r] = fmaf(hv.x, w0, fmaf(hv.y, w1, fmaf(hv.z, w2, fmaf(hv.w, w3, accl[r]))));
      accr[r] = fmaf(hv.x, v0, fmaf(hv.y, v1, fmaf(hv.z, v2, fmaf(hv.w, v3, accr[r]))));
    }
  }
  #pragma unroll
  for (int r = 0; r < 16; ++r){
    int row = row0 + rbase + r;
    if (row < N){
      xl[(size_t)row*64 + c] = accl[r];
      xr[(size_t)row*64 + c] = accr[r];
    }
  }
}

// ---------------- fused GATv2 aggregation + residual + LayerNorm (+relu) ----------------
__global__ __launch_bounds__(256) void k_gat(const float* __restrict__ xl, const float* __restrict__ xr,
                                             float* __restrict__ h, const int* __restrict__ row_ptr,
                                             const int* __restrict__ col,
                                             fp att, fp bg, fp lng, fp lnb, int N, int do_relu){
  int lane = threadIdx.x & 63;
  int node = blockIdx.x*4 + (threadIdx.x >> 6);
  if (node >= N) return;                 // whole wave exits together; no barriers below
  float att_v = att[lane];
  size_t base = (size_t)node*64 + lane;
  float xr_v = xr[base];
  float xls  = xl[base];
  // self loop initializes online-softmax state
  float t = xls + xr_v; t = t > 0.f ? t : NEGS*t;
  float p = t * att_v;
  p += __shfl_xor(p, 1); p += __shfl_xor(p, 2); p += __shfl_xor(p, 4); p += __shfl_xor(p, 8);
  float m = p, den = 1.f, acc = xls;
  int e0 = row_ptr[node], e1 = row_ptr[node+1];
  for (int e = e0; e < e1; ++e){
    int j = col[e];
    float xlv = xl[(size_t)j*64 + lane];
    float tt = xlv + xr_v; tt = tt > 0.f ? tt : NEGS*tt;
    float s = tt * att_v;
    s += __shfl_xor(s, 1); s += __shfl_xor(s, 2); s += __shfl_xor(s, 4); s += __shfl_xor(s, 8);
    float mn = fmaxf(m, s);
    float f = __expf(m - mn), w = __expf(s - mn);
    den = den*f + w;
    acc = acc*f + w*xlv;
    m = mn;
  }
  float o = acc/den + bg[lane] + h[base];
  // LayerNorm across the 64 lanes
  float sum = o;
  #pragma unroll
  for (int off = 1; off < 64; off <<= 1) sum += __shfl_xor(sum, off);
  float mean = sum * (1.f/64.f);
  float d = o - mean;
  float vs = d*d;
  #pragma unroll
  for (int off = 1; off < 64; off <<= 1) vs += __shfl_xor(vs, off);
  float var = vs * (1.f/64.f);
  float y = d * rsqrtf(var + LN_EPS) * lng[lane] + lnb[lane];
  if (do_relu) y = fmaxf(y, 0.f);
  h[base] = y;
}

// ---------------- gate MLP + per-graph atomic max ----------------
__global__ __launch_bounds__(256) void k_gate(const float* __restrict__ h, fp w1, fp b1, fp w2, fp b2,
                                              const int* __restrict__ batch,
                                              float* __restrict__ gate, unsigned* __restrict__ umax, int N){
  __shared__ float w1s[64*32];
  __shared__ float hrow[4][64];
  int tid = threadIdx.x;
  for (int i = tid*4; i < 2048; i += 1024) *(float4*)&w1s[i] = *(const float4*)&w1[i];
  int wave = tid >> 6, lane = tid & 63;
  int node = blockIdx.x*4 + wave;
  bool valid = node < N;
  hrow[wave][lane] = valid ? h[(size_t)node*64 + lane] : 0.f;
  __syncthreads();
  int j = lane & 31, half = lane >> 5;
  float s = 0.f;
  int k0 = half*32;
  #pragma unroll 8
  for (int k = k0; k < k0 + 32; ++k) s = fmaf(hrow[wave][k], w1s[k*32 + j], s);
  s += __shfl_xor(s, 32);
  float hid = fmaxf(s + b1[j], 0.f);
  float contrib = (half == 0) ? hid * w2[j] : 0.f;
  #pragma unroll
  for (int off = 1; off < 64; off <<= 1) contrib += __shfl_xor(contrib, off);
  if (valid && lane == 0){
    float v = contrib + b2[0];
    gate[node] = v;
    atomicMax(&umax[batch[node]], fenc(v));
  }
}

// ---------------- pooling accumulate: embsum[g] += exp(gate-gmax)*h ; gsum[g] += exp ----------------
__global__ __launch_bounds__(256) void k_emb(const float* __restrict__ h, const float* __restrict__ gate,
                                             const int* __restrict__ batch, const unsigned* __restrict__ umax,
                                             float* __restrict__ gsum, float* __restrict__ embsum, int N){
  int lane = threadIdx.x & 63;
  int wv = blockIdx.x*4 + (threadIdx.x >> 6);
  int s = wv*64;
  if (s >= N) return;
  int e = min(s + 64, N);
  int cur = batch[s];
  float gm = fdec(umax[cur]);
  float acc = 0.f, asum = 0.f;
  for (int i = s; i < e; ++i){
    int g = batch[i];                           // wave-uniform (batch sorted)
    if (g != cur){
      atomicAdd(&embsum[cur*64 + lane], acc);
      if (lane == 0) atomicAdd(&gsum[cur], asum);
      acc = 0.f; asum = 0.f; cur = g; gm = fdec(umax[g]);
    }
    float a = __expf(gate[i] - gm);
    acc = fmaf(a, h[(size_t)i*64 + lane], acc);
    asum += a;
  }
  atomicAdd(&embsum[cur*64 + lane], acc);
  if (lane == 0) atomicAdd(&gsum[cur], asum);
}

// ---------------- final: out = relu((embsum/gs) @ w_out + b_out) ----------------
__global__ __launch_bounds__(64) void k_out(const float* __restrict__ embsum, const float* __restrict__ gsum,
                                            fp w_out, fp b_out, float* __restrict__ out, int G){
  int g = blockIdx.x, lane = threadIdx.x;
  __shared__ float emb[64];
  float gs = gsum[g];
  float inv = (gs > 0.f) ? 1.f/gs : 1.f;
  emb[lane] = embsum[g*64 + lane] * inv;
  __syncthreads();
  float o2 = b_out[lane];
  #pragma unroll 8
  for (int d = 0; d < 64; ++d) o2 = fmaf(emb[d], w_out[d*64 + lane], o2);
  out[g*64 + lane] = fmaxf(o2, 0.f);
}

extern "C" void kernel_launch(void* const* d_in, const int* in_sizes, int n_in,
                              void* d_out, int out_size, void* d_ws, size_t ws_size,
                              hipStream_t stream) {
  const int N = in_sizes[0] / 24;
  const int E = in_sizes[1] / 2;
  const int G = out_size / 64;

  fp x      = (fp)d_in[0];
  const int* edge  = (const int*)d_in[1];
  const int* batch = (const int*)d_in[2];
  fp w_in   = (fp)d_in[3];
  fp b_in   = (fp)d_in[4];
  fp w_l    = (fp)d_in[5];
  fp b_l    = (fp)d_in[6];
  fp w_r    = (fp)d_in[7];
  fp b_r    = (fp)d_in[8];
  fp att    = (fp)d_in[9];
  fp b_gat  = (fp)d_in[10];
  fp ln_g   = (fp)d_in[11];
  fp ln_b   = (fp)d_in[12];
  fp w_g1   = (fp)d_in[13];
  fp b_g1   = (fp)d_in[14];
  fp w_g2   = (fp)d_in[15];
  fp b_g2   = (fp)d_in[16];
  fp w_out  = (fp)d_in[17];
  fp b_out  = (fp)d_in[18];
  float* out = (float*)d_out;

  char* wp = (char*)d_ws;
  auto alloc = [&](size_t bytes) -> char* {
    char* p = wp; wp += (bytes + 255) & ~(size_t)255; return p;
  };
  float* h       = (float*)alloc((size_t)N*64*sizeof(float));
  float* xl      = (float*)alloc((size_t)N*64*sizeof(float));
  float* xr      = (float*)alloc((size_t)N*64*sizeof(float));
  int*   col     = (int*)  alloc((size_t)E*sizeof(int));
  int*   row_ptr = (int*)  alloc((size_t)(N+1)*sizeof(int));
  int*   counts  = (int*)  alloc((size_t)N*sizeof(int));
  int*   scanned = (int*)  alloc((size_t)N*sizeof(int));
  int*   cursor  = (int*)  alloc((size_t)N*sizeof(int));
  int*   bsums   = (int*)  alloc(256*sizeof(int));
  float* gate    = (float*)alloc((size_t)N*sizeof(float));
  // pooling scratch, zeroed contiguously: umax[G] | gsum[G] | embsum[G*64]
  int poolN = G + G + G*64;
  unsigned* umax = (unsigned*)alloc((size_t)poolN*sizeof(float));
  float* gsum    = (float*)(umax + G);
  float* embsum  = (float*)(umax + 2*G);

  const int* srcA = edge;
  const int* dstA = edge + E;
  const int NB = (N + 255) / 256;

  k_in<<<(N + 3)/4, 256, 0, stream>>>(x, w_in, b_in, h, N);
  k_zero<<<NB, 256, 0, stream>>>(counts, N);
  k_zero<<<(poolN + 255)/256, 256, 0, stream>>>((int*)umax, poolN);
  k_hist<<<(E + 255)/256, 256, 0, stream>>>(dstA, counts, E);
  k_scan1<<<NB, 256, 0, stream>>>(counts, scanned, bsums, N);
  k_scan2<<<1, 256, 0, stream>>>(bsums, NB);
  k_scan3<<<NB, 256, 0, stream>>>(scanned, bsums, row_ptr, cursor, N);
  k_scatter<<<(E + 255)/256, 256, 0, stream>>>(srcA, dstA, row_ptr, cursor, col, E);

  for (int i = 0; i < 3; ++i){
    k_xfm<<<(N + 63)/64, 256, 0, stream>>>(h, w_l + i*4096, b_l + i*64, w_r + i*4096, b_r + i*64,
                                           xl, xr, N);
    k_gat<<<(N + 3)/4, 256, 0, stream>>>(xl, xr, h, row_ptr, col,
                                         att + i*64, b_gat + i*64, ln_g + i*64, ln_b + i*64,
                                         N, i < 2 ? 1 : 0);
  }
  k_gate<<<(N + 3)/4, 256, 0, stream>>>(h, w_g1, b_g1, w_g2, b_g2, batch, gate, umax, N);
  k_emb<<<(N + 255)/256, 256, 0, stream>>>(h, gate, batch, umax, gsum, embsum, N);
  k_out<<<G, 64, 0, stream>>>(embsum, gsum, w_out, b_out, out, G);
}

// Round 5
// 953.033 us; speedup vs baseline: 1.3519x; 1.3519x over previous
//
#include <hip/hip_runtime.h>

#define NEGS   0.2f
#define LN_EPS 1e-5f

typedef const float* __restrict__ fp;

// ---------------- input transform: h = relu(x @ w_in + b_in) ----------------
__global__ __launch_bounds__(256) void k_in(fp x, fp w, fp b, float* __restrict__ h, int N){
  __shared__ float ws[24*64];
  __shared__ float bs[64];
  __shared__ float xs[4][24];
  int tid = threadIdx.x;
  for (int i = tid; i < 24*64; i += 256) ws[i] = w[i];
  if (tid < 64) bs[tid] = b[tid];
  int r = tid >> 6, c = tid & 63;
  int row = blockIdx.x*4 + r;
  if (c < 24 && row < N) xs[r][c] = x[row*24 + c];
  __syncthreads();
  if (row < N){
    float acc = bs[c];
    #pragma unroll
    for (int k = 0; k < 24; ++k) acc = fmaf(xs[r][k], ws[k*64 + c], acc);
    h[row*64 + c] = fmaxf(acc, 0.f);
  }
}

// ---------------- CSR build ----------------
__global__ void k_zero(int* __restrict__ p, int n){
  int i = blockIdx.x*256 + threadIdx.x;
  if (i < n) p[i] = 0;
}

__global__ void k_hist(const int* __restrict__ dst, int* __restrict__ counts, int E){
  int e = blockIdx.x*256 + threadIdx.x;
  if (e < E) atomicAdd(&counts[dst[e]], 1);
}

__global__ __launch_bounds__(256) void k_scan1(const int* __restrict__ counts, int* __restrict__ scanned,
                                               int* __restrict__ bsums, int N){
  __shared__ int s[256];
  int i = blockIdx.x*256 + threadIdx.x;
  int v = (i < N) ? counts[i] : 0;
  s[threadIdx.x] = v;
  __syncthreads();
  for (int off = 1; off < 256; off <<= 1){
    int t = (threadIdx.x >= off) ? s[threadIdx.x - off] : 0;
    __syncthreads();
    s[threadIdx.x] += t;
    __syncthreads();
  }
  if (i < N) scanned[i] = s[threadIdx.x];
  if (threadIdx.x == 255) bsums[blockIdx.x] = s[255];
}

__global__ __launch_bounds__(256) void k_scan2(int* __restrict__ bsums, int NB){
  __shared__ int s[256];
  int v = (threadIdx.x < NB) ? bsums[threadIdx.x] : 0;
  s[threadIdx.x] = v;
  __syncthreads();
  for (int off = 1; off < 256; off <<= 1){
    int t = (threadIdx.x >= off) ? s[threadIdx.x - off] : 0;
    __syncthreads();
    s[threadIdx.x] += t;
    __syncthreads();
  }
  if (threadIdx.x < NB) bsums[threadIdx.x] = s[threadIdx.x] - v;
}

__global__ void k_scan3(const int* __restrict__ scanned, const int* __restrict__ bsums,
                        int* __restrict__ row_ptr, int* __restrict__ cursor, int N){
  int i = blockIdx.x*256 + threadIdx.x;
  if (i < N){
    row_ptr[i+1] = scanned[i] + bsums[blockIdx.x];
    cursor[i] = 0;
    if (i == 0) row_ptr[0] = 0;
  }
}

__global__ void k_scatter(const int* __restrict__ srcA, const int* __restrict__ dstA,
                          const int* __restrict__ row_ptr, int* __restrict__ cursor,
                          int* __restrict__ col, int E){
  int e = blockIdx.x*256 + threadIdx.x;
  if (e < E){
    int d = dstA[e];
    int p = atomicAdd(&cursor[d], 1);
    col[row_ptr[d] + p] = srcA[e];
  }
}

// ---------------- per-layer transforms: xl = h@wl+bl, xr = h@wr+br ----------------
__global__ __launch_bounds__(256) void k_xfm(const float* __restrict__ h, fp wlg, fp blg, fp wrg, fp brg,
                                             float* __restrict__ xl, float* __restrict__ xr, int N){
  __shared__ float wl[4096];
  __shared__ float wr[4096];
  __shared__ float hs[64*64];
  int tid = threadIdx.x;
  for (int i = tid*4; i < 4096; i += 1024){
    *(float4*)&wl[i] = *(const float4*)&wlg[i];
    *(float4*)&wr[i] = *(const float4*)&wrg[i];
  }
  int row0 = blockIdx.x*64;
  int nrows = min(64, N - row0);
  int lim = nrows*64;
  for (int i = tid*4; i < lim; i += 1024)
    *(float4*)&hs[i] = *(const float4*)&h[(size_t)row0*64 + i];
  __syncthreads();
  int wave = tid >> 6, c = tid & 63;
  float blv = blg[c], brv = brg[c];
  float accl[16], accr[16];
  #pragma unroll
  for (int r = 0; r < 16; ++r){ accl[r] = blv; accr[r] = brv; }
  int rbase = wave*16;
  #pragma unroll 4
  for (int k = 0; k < 64; k += 4){
    float w0 = wl[k*64+c], w1 = wl[(k+1)*64+c], w2 = wl[(k+2)*64+c], w3 = wl[(k+3)*64+c];
    float v0 = wr[k*64+c], v1 = wr[(k+1)*64+c], v2 = wr[(k+2)*64+c], v3 = wr[(k+3)*64+c];
    #pragma unroll
    for (int r = 0; r < 16; ++r){
      float4 hv = *(const float4*)&hs[(rbase + r)*64 + k];
      accl[r] = fmaf(hv.x, w0, fmaf(hv.y, w1, fmaf(hv.z, w2, fmaf(hv.w, w3, accl[r]))));
      accr[r] = fmaf(hv.x, v0, fmaf(hv.y, v1, fmaf(hv.z, v2, fmaf(hv.w, v3, accr[r]))));
    }
  }
  #pragma unroll
  for (int r = 0; r < 16; ++r){
    int row = row0 + rbase + r;
    if (row < N){
      xl[(size_t)row*64 + c] = accl[r];
      xr[(size_t)row*64 + c] = accr[r];
    }
  }
}

// ---------------- fused GATv2 aggregation + residual + LayerNorm (+relu) ----------------
__global__ __launch_bounds__(256) void k_gat(const float* __restrict__ xl, const float* __restrict__ xr,
                                             float* __restrict__ h, const int* __restrict__ row_ptr,
                                             const int* __restrict__ col,
                                             fp att, fp bg, fp lng, fp lnb, int N, int do_relu){
  int lane = threadIdx.x & 63;
  int node = blockIdx.x*4 + (threadIdx.x >> 6);
  if (node >= N) return;                 // whole wave exits together; no barriers below
  float att_v = att[lane];
  size_t base = (size_t)node*64 + lane;
  float xr_v = xr[base];
  float xls  = xl[base];
  // self loop initializes online-softmax state
  float t = xls + xr_v; t = t > 0.f ? t : NEGS*t;
  float p = t * att_v;
  p += __shfl_xor(p, 1); p += __shfl_xor(p, 2); p += __shfl_xor(p, 4); p += __shfl_xor(p, 8);
  float m = p, den = 1.f, acc = xls;
  int e0 = row_ptr[node], e1 = row_ptr[node+1];
  for (int e = e0; e < e1; ++e){
    int j = col[e];
    float xlv = xl[(size_t)j*64 + lane];
    float tt = xlv + xr_v; tt = tt > 0.f ? tt : NEGS*tt;
    float s = tt * att_v;
    s += __shfl_xor(s, 1); s += __shfl_xor(s, 2); s += __shfl_xor(s, 4); s += __shfl_xor(s, 8);
    float mn = fmaxf(m, s);
    float f = __expf(m - mn), w = __expf(s - mn);
    den = den*f + w;
    acc = acc*f + w*xlv;
    m = mn;
  }
  float o = acc/den + bg[lane] + h[base];
  // LayerNorm across the 64 lanes
  float sum = o;
  #pragma unroll
  for (int off = 1; off < 64; off <<= 1) sum += __shfl_xor(sum, off);
  float mean = sum * (1.f/64.f);
  float d = o - mean;
  float vs = d*d;
  #pragma unroll
  for (int off = 1; off < 64; off <<= 1) vs += __shfl_xor(vs, off);
  float var = vs * (1.f/64.f);
  float y = d * rsqrtf(var + LN_EPS) * lng[lane] + lnb[lane];
  if (do_relu) y = fmaxf(y, 0.f);
  h[base] = y;
}

// ---------------- gate MLP (no atomics): gate = relu(h@w_g1+b_g1)@w_g2 + b_g2 ----------------
__global__ __launch_bounds__(256) void k_gate(const float* __restrict__ h, fp w1, fp b1, fp w2, fp b2,
                                              float* __restrict__ gate, int N){
  __shared__ float w1s[2048];
  __shared__ float hrow[16][64];
  int tid = threadIdx.x;
  for (int i = tid*4; i < 2048; i += 1024) *(float4*)&w1s[i] = *(const float4*)&w1[i];
  int base = blockIdx.x*16;
  int nrows = min(16, N - base);
  int lim = nrows*64;
  for (int i = tid*4; i < lim; i += 1024)
    *(float4*)&hrow[0][i] = *(const float4*)&h[(size_t)base*64 + i];
  __syncthreads();
  int wave = tid >> 6, lane = tid & 63;
  int j = lane & 31, half = lane >> 5;
  float b1v = b1[j], w2v = w2[j], b2v = b2[0];
  int k0 = half*32;
  #pragma unroll
  for (int it = 0; it < 4; ++it){
    int r = wave*4 + it;
    int node = base + r;
    if (node >= N) break;                // wave-uniform
    float s = 0.f;
    #pragma unroll 8
    for (int k = k0; k < k0 + 32; ++k) s = fmaf(hrow[r][k], w1s[k*32 + j], s);
    s += __shfl_xor(s, 32);
    float hid = fmaxf(s + b1v, 0.f);
    float contrib = (half == 0) ? hid * w2v : 0.f;
    #pragma unroll
    for (int off = 1; off < 64; off <<= 1) contrib += __shfl_xor(contrib, off);
    if (lane == 0) gate[node] = contrib + b2v;
  }
}

// ---------------- per-graph gate max (no atomics; batch sorted) ----------------
__global__ __launch_bounds__(256) void k_gmax(const float* __restrict__ gate, const int* __restrict__ batch,
                                              float* __restrict__ gmax, int N){
  int g = blockIdx.x, tid = threadIdx.x;
  int lo = 0, hi = N;
  while (lo < hi){ int mid = (lo + hi) >> 1; if (batch[mid] < g) lo = mid + 1; else hi = mid; }
  int start = lo;
  hi = N;
  while (lo < hi){ int mid = (lo + hi) >> 1; if (batch[mid] < g + 1) lo = mid + 1; else hi = mid; }
  int end = lo;
  float m = -3.4e38f;
  for (int i = start + tid; i < end; i += 256) m = fmaxf(m, gate[i]);
  #pragma unroll
  for (int off = 1; off < 64; off <<= 1) m = fmaxf(m, __shfl_xor(m, off));
  __shared__ float ws[4];
  if ((tid & 63) == 0) ws[tid >> 6] = m;
  __syncthreads();
  if (tid == 0) gmax[g] = fmaxf(fmaxf(ws[0], ws[1]), fmaxf(ws[2], ws[3]));
}

// ---------------- pooling accumulate: embsum[g] += exp(gate-gmax)*h ; gsum[g] += exp ----------------
__global__ __launch_bounds__(256) void k_emb(const float* __restrict__ h, const float* __restrict__ gate,
                                             const int* __restrict__ batch, const float* __restrict__ gmax,
                                             float* __restrict__ gsum, float* __restrict__ embsum, int N){
  int lane = threadIdx.x & 63;
  int wv = blockIdx.x*4 + (threadIdx.x >> 6);
  int s = wv*64;
  if (s >= N) return;
  int e = min(s + 64, N);
  int cur = batch[s];
  float gm = gmax[cur];
  float acc = 0.f, asum = 0.f;
  for (int i = s; i < e; ++i){
    int g = batch[i];                           // wave-uniform (batch sorted)
    if (g != cur){
      atomicAdd(&embsum[cur*64 + lane], acc);
      if (lane == 0) atomicAdd(&gsum[cur], asum);
      acc = 0.f; asum = 0.f; cur = g; gm = gmax[g];
    }
    float a = __expf(gate[i] - gm);
    acc = fmaf(a, h[(size_t)i*64 + lane], acc);
    asum += a;
  }
  atomicAdd(&embsum[cur*64 + lane], acc);
  if (lane == 0) atomicAdd(&gsum[cur], asum);
}

// ---------------- final: out = relu((embsum/gs) @ w_out + b_out) ----------------
__global__ __launch_bounds__(64) void k_out(const float* __restrict__ embsum, const float* __restrict__ gsum,
                                            fp w_out, fp b_out, float* __restrict__ out, int G){
  int g = blockIdx.x, lane = threadIdx.x;
  __shared__ float emb[64];
  float gs = gsum[g];
  float inv = (gs > 0.f) ? 1.f/gs : 1.f;
  emb[lane] = embsum[g*64 + lane] * inv;
  __syncthreads();
  float o2 = b_out[lane];
  #pragma unroll 8
  for (int d = 0; d < 64; ++d) o2 = fmaf(emb[d], w_out[d*64 + lane], o2);
  out[g*64 + lane] = fmaxf(o2, 0.f);
}

extern "C" void kernel_launch(void* const* d_in, const int* in_sizes, int n_in,
                              void* d_out, int out_size, void* d_ws, size_t ws_size,
                              hipStream_t stream) {
  const int N = in_sizes[0] / 24;
  const int E = in_sizes[1] / 2;
  const int G = out_size / 64;

  fp x      = (fp)d_in[0];
  const int* edge  = (const int*)d_in[1];
  const int* batch = (const int*)d_in[2];
  fp w_in   = (fp)d_in[3];
  fp b_in   = (fp)d_in[4];
  fp w_l    = (fp)d_in[5];
  fp b_l    = (fp)d_in[6];
  fp w_r    = (fp)d_in[7];
  fp b_r    = (fp)d_in[8];
  fp att    = (fp)d_in[9];
  fp b_gat  = (fp)d_in[10];
  fp ln_g   = (fp)d_in[11];
  fp ln_b   = (fp)d_in[12];
  fp w_g1   = (fp)d_in[13];
  fp b_g1   = (fp)d_in[14];
  fp w_g2   = (fp)d_in[15];
  fp b_g2   = (fp)d_in[16];
  fp w_out  = (fp)d_in[17];
  fp b_out  = (fp)d_in[18];
  float* out = (float*)d_out;

  char* wp = (char*)d_ws;
  auto alloc = [&](size_t bytes) -> char* {
    char* p = wp; wp += (bytes + 255) & ~(size_t)255; return p;
  };
  float* h       = (float*)alloc((size_t)N*64*sizeof(float));
  float* xl      = (float*)alloc((size_t)N*64*sizeof(float));
  float* xr      = (float*)alloc((size_t)N*64*sizeof(float));
  int*   col     = (int*)  alloc((size_t)E*sizeof(int));
  int*   row_ptr = (int*)  alloc((size_t)(N+1)*sizeof(int));
  int*   counts  = (int*)  alloc((size_t)N*sizeof(int));
  int*   scanned = (int*)  alloc((size_t)N*sizeof(int));
  int*   cursor  = (int*)  alloc((size_t)N*sizeof(int));
  int*   bsums   = (int*)  alloc(256*sizeof(int));
  float* gate    = (float*)alloc((size_t)N*sizeof(float));
  float* gmax    = (float*)alloc((size_t)G*sizeof(float));
  // pooling accumulators, zeroed contiguously: gsum[G] | embsum[G*64]
  int poolN = G + G*64;
  float* gsum    = (float*)alloc((size_t)poolN*sizeof(float));
  float* embsum  = gsum + G;

  const int* srcA = edge;
  const int* dstA = edge + E;
  const int NB = (N + 255) / 256;

  k_in<<<(N + 3)/4, 256, 0, stream>>>(x, w_in, b_in, h, N);
  k_zero<<<NB, 256, 0, stream>>>(counts, N);
  k_zero<<<(poolN + 255)/256, 256, 0, stream>>>((int*)gsum, poolN);
  k_hist<<<(E + 255)/256, 256, 0, stream>>>(dstA, counts, E);
  k_scan1<<<NB, 256, 0, stream>>>(counts, scanned, bsums, N);
  k_scan2<<<1, 256, 0, stream>>>(bsums, NB);
  k_scan3<<<NB, 256, 0, stream>>>(scanned, bsums, row_ptr, cursor, N);
  k_scatter<<<(E + 255)/256, 256, 0, stream>>>(srcA, dstA, row_ptr, cursor, col, E);

  for (int i = 0; i < 3; ++i){
    k_xfm<<<(N + 63)/64, 256, 0, stream>>>(h, w_l + i*4096, b_l + i*64, w_r + i*4096, b_r + i*64,
                                           xl, xr, N);
    k_gat<<<(N + 3)/4, 256, 0, stream>>>(xl, xr, h, row_ptr, col,
                                         att + i*64, b_gat + i*64, ln_g + i*64, ln_b + i*64,
                                         N, i < 2 ? 1 : 0);
  }
  k_gate<<<(N + 15)/16, 256, 0, stream>>>(h, w_g1, b_g1, w_g2, b_g2, gate, N);
  k_gmax<<<G, 256, 0, stream>>>(gate, batch, gmax, N);
  k_emb<<<(N + 255)/256, 256, 0, stream>>>(h, gate, batch, gmax, gsum, embsum, N);
  k_out<<<G, 64, 0, stream>>>(embsum, gsum, w_out, b_out, out, G);
}

// Round 6
// 662.277 us; speedup vs baseline: 1.9454x; 1.4390x over previous
//
#include <hip/hip_runtime.h>

#define NEGS   0.2f
#define LN_EPS 1e-5f

typedef const float* __restrict__ fp;

// ---------------- input transform: h = relu(x @ w_in + b_in) ----------------
__global__ __launch_bounds__(256) void k_in(fp x, fp w, fp b, float* __restrict__ h, int N){
  __shared__ float ws[24*64];
  __shared__ float bs[64];
  __shared__ float xs[4][24];
  int tid = threadIdx.x;
  for (int i = tid; i < 24*64; i += 256) ws[i] = w[i];
  if (tid < 64) bs[tid] = b[tid];
  int r = tid >> 6, c = tid & 63;
  int row = blockIdx.x*4 + r;
  if (c < 24 && row < N) xs[r][c] = x[row*24 + c];
  __syncthreads();
  if (row < N){
    float acc = bs[c];
    #pragma unroll
    for (int k = 0; k < 24; ++k) acc = fmaf(xs[r][k], ws[k*64 + c], acc);
    h[row*64 + c] = fmaxf(acc, 0.f);
  }
}

// ---------------- CSR build ----------------
__global__ void k_zero(int* __restrict__ p, int n){
  int i = blockIdx.x*256 + threadIdx.x;
  if (i < n) p[i] = 0;
}

__global__ void k_hist(const int* __restrict__ dst, int* __restrict__ counts, int E){
  int e = blockIdx.x*256 + threadIdx.x;
  if (e < E) atomicAdd(&counts[dst[e]], 1);
}

__global__ __launch_bounds__(256) void k_scan1(const int* __restrict__ counts, int* __restrict__ scanned,
                                               int* __restrict__ bsums, int N){
  __shared__ int s[256];
  int i = blockIdx.x*256 + threadIdx.x;
  int v = (i < N) ? counts[i] : 0;
  s[threadIdx.x] = v;
  __syncthreads();
  for (int off = 1; off < 256; off <<= 1){
    int t = (threadIdx.x >= off) ? s[threadIdx.x - off] : 0;
    __syncthreads();
    s[threadIdx.x] += t;
    __syncthreads();
  }
  if (i < N) scanned[i] = s[threadIdx.x];
  if (threadIdx.x == 255) bsums[blockIdx.x] = s[255];
}

__global__ __launch_bounds__(256) void k_scan2(int* __restrict__ bsums, int NB){
  __shared__ int s[256];
  int v = (threadIdx.x < NB) ? bsums[threadIdx.x] : 0;
  s[threadIdx.x] = v;
  __syncthreads();
  for (int off = 1; off < 256; off <<= 1){
    int t = (threadIdx.x >= off) ? s[threadIdx.x - off] : 0;
    __syncthreads();
    s[threadIdx.x] += t;
    __syncthreads();
  }
  if (threadIdx.x < NB) bsums[threadIdx.x] = s[threadIdx.x] - v;
}

__global__ void k_scan3(const int* __restrict__ scanned, const int* __restrict__ bsums,
                        int* __restrict__ row_ptr, int* __restrict__ cursor, int N){
  int i = blockIdx.x*256 + threadIdx.x;
  if (i < N){
    row_ptr[i+1] = scanned[i] + bsums[blockIdx.x];
    cursor[i] = 0;
    if (i == 0) row_ptr[0] = 0;
  }
}

__global__ void k_scatter(const int* __restrict__ srcA, const int* __restrict__ dstA,
                          const int* __restrict__ row_ptr, int* __restrict__ cursor,
                          int* __restrict__ col, int E){
  int e = blockIdx.x*256 + threadIdx.x;
  if (e < E){
    int d = dstA[e];
    int p = atomicAdd(&cursor[d], 1);
    col[row_ptr[d] + p] = srcA[e];
  }
}

// ---------------- per-layer transforms: xl = h@wl+bl, xr = h@wr+br ----------------
__global__ __launch_bounds__(256) void k_xfm(const float* __restrict__ h, fp wlg, fp blg, fp wrg, fp brg,
                                             float* __restrict__ xl, float* __restrict__ xr, int N){
  __shared__ float wl[4096];
  __shared__ float wr[4096];
  __shared__ float hs[64*64];
  int tid = threadIdx.x;
  for (int i = tid*4; i < 4096; i += 1024){
    *(float4*)&wl[i] = *(const float4*)&wlg[i];
    *(float4*)&wr[i] = *(const float4*)&wrg[i];
  }
  int row0 = blockIdx.x*64;
  int nrows = min(64, N - row0);
  int lim = nrows*64;
  for (int i = tid*4; i < lim; i += 1024)
    *(float4*)&hs[i] = *(const float4*)&h[(size_t)row0*64 + i];
  __syncthreads();
  int wave = tid >> 6, c = tid & 63;
  float blv = blg[c], brv = brg[c];
  float accl[16], accr[16];
  #pragma unroll
  for (int r = 0; r < 16; ++r){ accl[r] = blv; accr[r] = brv; }
  int rbase = wave*16;
  #pragma unroll 4
  for (int k = 0; k < 64; k += 4){
    float w0 = wl[k*64+c], w1 = wl[(k+1)*64+c], w2 = wl[(k+2)*64+c], w3 = wl[(k+3)*64+c];
    float v0 = wr[k*64+c], v1 = wr[(k+1)*64+c], v2 = wr[(k+2)*64+c], v3 = wr[(k+3)*64+c];
    #pragma unroll
    for (int r = 0; r < 16; ++r){
      float4 hv = *(const float4*)&hs[(rbase + r)*64 + k];
      accl[r] = fmaf(hv.x, w0, fmaf(hv.y, w1, fmaf(hv.z, w2, fmaf(hv.w, w3, accl[r]))));
      accr[r] = fmaf(hv.x, v0, fmaf(hv.y, v1, fmaf(hv.z, v2, fmaf(hv.w, v3, accr[r]))));
    }
  }
  #pragma unroll
  for (int r = 0; r < 16; ++r){
    int row = row0 + rbase + r;
    if (row < N){
      xl[(size_t)row*64 + c] = accl[r];
      xr[(size_t)row*64 + c] = accr[r];
    }
  }
}

// ---------------- fused GATv2 aggregation + residual + LayerNorm (+relu) ----------------
// Softmax shift = self-loop score (wave-local, no running max) -> edge iterations are
// independent; 4-way unroll with separate partial accumulators breaks all FP chains.
__global__ __launch_bounds__(256) void k_gat(const float* __restrict__ xl, const float* __restrict__ xr,
                                             float* __restrict__ h, const int* __restrict__ row_ptr,
                                             const int* __restrict__ col,
                                             fp att, fp bg, fp lng, fp lnb, int N, int do_relu){
  int lane = threadIdx.x & 63;
  int node = blockIdx.x*4 + (threadIdx.x >> 6);
  if (node >= N) return;                 // whole wave exits together; no barriers below
  float att_v = att[lane];
  size_t base = (size_t)node*64 + lane;
  float xr_v = xr[base];
  float xls  = xl[base];
  // self-loop score = fixed softmax shift
  float t = xls + xr_v; t = fmaxf(t, NEGS*t);
  float p = t * att_v;
  p += __shfl_xor(p, 1); p += __shfl_xor(p, 2); p += __shfl_xor(p, 4); p += __shfl_xor(p, 8);
  const float m = p;
  int e0 = row_ptr[node], e1 = row_ptr[node+1];
  float den0 = 0.f, den1 = 0.f, den2 = 0.f, den3 = 0.f;
  float ac0 = 0.f, ac1 = 0.f, ac2 = 0.f, ac3 = 0.f;
  int e = e0;
  for (; e + 4 <= e1; e += 4){
    int j0 = col[e], j1 = col[e+1], j2 = col[e+2], j3 = col[e+3];
    float v0 = xl[(size_t)j0*64 + lane];
    float v1 = xl[(size_t)j1*64 + lane];
    float v2 = xl[(size_t)j2*64 + lane];
    float v3 = xl[(size_t)j3*64 + lane];
    float t0 = v0 + xr_v; t0 = fmaxf(t0, NEGS*t0); float s0 = t0*att_v;
    float t1 = v1 + xr_v; t1 = fmaxf(t1, NEGS*t1); float s1 = t1*att_v;
    float t2 = v2 + xr_v; t2 = fmaxf(t2, NEGS*t2); float s2 = t2*att_v;
    float t3 = v3 + xr_v; t3 = fmaxf(t3, NEGS*t3); float s3 = t3*att_v;
    s0 += __shfl_xor(s0, 1); s0 += __shfl_xor(s0, 2); s0 += __shfl_xor(s0, 4); s0 += __shfl_xor(s0, 8);
    s1 += __shfl_xor(s1, 1); s1 += __shfl_xor(s1, 2); s1 += __shfl_xor(s1, 4); s1 += __shfl_xor(s1, 8);
    s2 += __shfl_xor(s2, 1); s2 += __shfl_xor(s2, 2); s2 += __shfl_xor(s2, 4); s2 += __shfl_xor(s2, 8);
    s3 += __shfl_xor(s3, 1); s3 += __shfl_xor(s3, 2); s3 += __shfl_xor(s3, 4); s3 += __shfl_xor(s3, 8);
    float w0 = __expf(s0 - m);
    float w1 = __expf(s1 - m);
    float w2 = __expf(s2 - m);
    float w3 = __expf(s3 - m);
    den0 += w0; ac0 = fmaf(w0, v0, ac0);
    den1 += w1; ac1 = fmaf(w1, v1, ac1);
    den2 += w2; ac2 = fmaf(w2, v2, ac2);
    den3 += w3; ac3 = fmaf(w3, v3, ac3);
  }
  for (; e < e1; ++e){
    int j = col[e];
    float v = xl[(size_t)j*64 + lane];
    float tt = v + xr_v; tt = fmaxf(tt, NEGS*tt);
    float s = tt * att_v;
    s += __shfl_xor(s, 1); s += __shfl_xor(s, 2); s += __shfl_xor(s, 4); s += __shfl_xor(s, 8);
    float w = __expf(s - m);
    den0 += w; ac0 = fmaf(w, v, ac0);
  }
  float den = 1.f + ((den0 + den1) + (den2 + den3));  // self-loop contributes exp(0)=1
  float acc = xls + ((ac0 + ac1) + (ac2 + ac3));
  float o = acc/den + bg[lane] + h[base];
  // LayerNorm across the 64 lanes
  float sum = o;
  #pragma unroll
  for (int off = 1; off < 64; off <<= 1) sum += __shfl_xor(sum, off);
  float mean = sum * (1.f/64.f);
  float d = o - mean;
  float vs = d*d;
  #pragma unroll
  for (int off = 1; off < 64; off <<= 1) vs += __shfl_xor(vs, off);
  float var = vs * (1.f/64.f);
  float y = d * rsqrtf(var + LN_EPS) * lng[lane] + lnb[lane];
  if (do_relu) y = fmaxf(y, 0.f);
  h[base] = y;
}

// ---------------- gate MLP (no atomics): gate = relu(h@w_g1+b_g1)@w_g2 + b_g2 ----------------
__global__ __launch_bounds__(256) void k_gate(const float* __restrict__ h, fp w1, fp b1, fp w2, fp b2,
                                              float* __restrict__ gate, int N){
  __shared__ float w1s[2048];
  __shared__ float hrow[16][64];
  int tid = threadIdx.x;
  for (int i = tid*4; i < 2048; i += 1024) *(float4*)&w1s[i] = *(const float4*)&w1[i];
  int base = blockIdx.x*16;
  int nrows = min(16, N - base);
  int lim = nrows*64;
  for (int i = tid*4; i < lim; i += 1024)
    *(float4*)&hrow[0][i] = *(const float4*)&h[(size_t)base*64 + i];
  __syncthreads();
  int wave = tid >> 6, lane = tid & 63;
  int j = lane & 31, half = lane >> 5;
  float b1v = b1[j], w2v = w2[j], b2v = b2[0];
  int k0 = half*32;
  #pragma unroll
  for (int it = 0; it < 4; ++it){
    int r = wave*4 + it;
    int node = base + r;
    if (node >= N) break;                // wave-uniform
    float s = 0.f;
    #pragma unroll 8
    for (int k = k0; k < k0 + 32; ++k) s = fmaf(hrow[r][k], w1s[k*32 + j], s);
    s += __shfl_xor(s, 32);
    float hid = fmaxf(s + b1v, 0.f);
    float contrib = (half == 0) ? hid * w2v : 0.f;
    #pragma unroll
    for (int off = 1; off < 64; off <<= 1) contrib += __shfl_xor(contrib, off);
    if (lane == 0) gate[node] = contrib + b2v;
  }
}

// ---------------- per-graph gate max (no atomics; batch sorted) ----------------
__global__ __launch_bounds__(256) void k_gmax(const float* __restrict__ gate, const int* __restrict__ batch,
                                              float* __restrict__ gmax, int N){
  int g = blockIdx.x, tid = threadIdx.x;
  int lo = 0, hi = N;
  while (lo < hi){ int mid = (lo + hi) >> 1; if (batch[mid] < g) lo = mid + 1; else hi = mid; }
  int start = lo;
  hi = N;
  while (lo < hi){ int mid = (lo + hi) >> 1; if (batch[mid] < g + 1) lo = mid + 1; else hi = mid; }
  int end = lo;
  float m = -3.4e38f;
  for (int i = start + tid; i < end; i += 256) m = fmaxf(m, gate[i]);
  #pragma unroll
  for (int off = 1; off < 64; off <<= 1) m = fmaxf(m, __shfl_xor(m, off));
  __shared__ float ws[4];
  if ((tid & 63) == 0) ws[tid >> 6] = m;
  __syncthreads();
  if (tid == 0) gmax[g] = fmaxf(fmaxf(ws[0], ws[1]), fmaxf(ws[2], ws[3]));
}

// ---------------- pooling accumulate: embsum[g] += exp(gate-gmax)*h ; gsum[g] += exp ----------------
__global__ __launch_bounds__(256) void k_emb(const float* __restrict__ h, const float* __restrict__ gate,
                                             const int* __restrict__ batch, const float* __restrict__ gmax,
                                             float* __restrict__ gsum, float* __restrict__ embsum, int N){
  int lane = threadIdx.x & 63;
  int wv = blockIdx.x*4 + (threadIdx.x >> 6);
  int s = wv*64;
  if (s >= N) return;
  int e = min(s + 64, N);
  int cur = batch[s];
  float gm = gmax[cur];
  float acc = 0.f, asum = 0.f;
  for (int i = s; i < e; ++i){
    int g = batch[i];                           // wave-uniform (batch sorted)
    if (g != cur){
      atomicAdd(&embsum[cur*64 + lane], acc);
      if (lane == 0) atomicAdd(&gsum[cur], asum);
      acc = 0.f; asum = 0.f; cur = g; gm = gmax[g];
    }
    float a = __expf(gate[i] - gm);
    acc = fmaf(a, h[(size_t)i*64 + lane], acc);
    asum += a;
  }
  atomicAdd(&embsum[cur*64 + lane], acc);
  if (lane == 0) atomicAdd(&gsum[cur], asum);
}

// ---------------- final: out = relu((embsum/gs) @ w_out + b_out) ----------------
__global__ __launch_bounds__(64) void k_out(const float* __restrict__ embsum, const float* __restrict__ gsum,
                                            fp w_out, fp b_out, float* __restrict__ out, int G){
  int g = blockIdx.x, lane = threadIdx.x;
  __shared__ float emb[64];
  float gs = gsum[g];
  float inv = (gs > 0.f) ? 1.f/gs : 1.f;
  emb[lane] = embsum[g*64 + lane] * inv;
  __syncthreads();
  float o2 = b_out[lane];
  #pragma unroll 8
  for (int d = 0; d < 64; ++d) o2 = fmaf(emb[d], w_out[d*64 + lane], o2);
  out[g*64 + lane] = fmaxf(o2, 0.f);
}

extern "C" void kernel_launch(void* const* d_in, const int* in_sizes, int n_in,
                              void* d_out, int out_size, void* d_ws, size_t ws_size,
                              hipStream_t stream) {
  const int N = in_sizes[0] / 24;
  const int E = in_sizes[1] / 2;
  const int G = out_size / 64;

  fp x      = (fp)d_in[0];
  const int* edge  = (const int*)d_in[1];
  const int* batch = (const int*)d_in[2];
  fp w_in   = (fp)d_in[3];
  fp b_in   = (fp)d_in[4];
  fp w_l    = (fp)d_in[5];
  fp b_l    = (fp)d_in[6];
  fp w_r    = (fp)d_in[7];
  fp b_r    = (fp)d_in[8];
  fp att    = (fp)d_in[9];
  fp b_gat  = (fp)d_in[10];
  fp ln_g   = (fp)d_in[11];
  fp ln_b   = (fp)d_in[12];
  fp w_g1   = (fp)d_in[13];
  fp b_g1   = (fp)d_in[14];
  fp w_g2   = (fp)d_in[15];
  fp b_g2   = (fp)d_in[16];
  fp w_out  = (fp)d_in[17];
  fp b_out  = (fp)d_in[18];
  float* out = (float*)d_out;

  char* wp = (char*)d_ws;
  auto alloc = [&](size_t bytes) -> char* {
    char* p = wp; wp += (bytes + 255) & ~(size_t)255; return p;
  };
  float* h       = (float*)alloc((size_t)N*64*sizeof(float));
  float* xl      = (float*)alloc((size_t)N*64*sizeof(float));
  float* xr      = (float*)alloc((size_t)N*64*sizeof(float));
  int*   col     = (int*)  alloc((size_t)E*sizeof(int));
  int*   row_ptr = (int*)  alloc((size_t)(N+1)*sizeof(int));
  int*   counts  = (int*)  alloc((size_t)N*sizeof(int));
  int*   scanned = (int*)  alloc((size_t)N*sizeof(int));
  int*   cursor  = (int*)  alloc((size_t)N*sizeof(int));
  int*   bsums   = (int*)  alloc(256*sizeof(int));
  float* gate    = (float*)alloc((size_t)N*sizeof(float));
  float* gmax    = (float*)alloc((size_t)G*sizeof(float));
  // pooling accumulators, zeroed contiguously: gsum[G] | embsum[G*64]
  int poolN = G + G*64;
  float* gsum    = (float*)alloc((size_t)poolN*sizeof(float));
  float* embsum  = gsum + G;

  const int* srcA = edge;
  const int* dstA = edge + E;
  const int NB = (N + 255) / 256;

  k_in<<<(N + 3)/4, 256, 0, stream>>>(x, w_in, b_in, h, N);
  k_zero<<<NB, 256, 0, stream>>>(counts, N);
  k_zero<<<(poolN + 255)/256, 256, 0, stream>>>((int*)gsum, poolN);
  k_hist<<<(E + 255)/256, 256, 0, stream>>>(dstA, counts, E);
  k_scan1<<<NB, 256, 0, stream>>>(counts, scanned, bsums, N);
  k_scan2<<<1, 256, 0, stream>>>(bsums, NB);
  k_scan3<<<NB, 256, 0, stream>>>(scanned, bsums, row_ptr, cursor, N);
  k_scatter<<<(E + 255)/256, 256, 0, stream>>>(srcA, dstA, row_ptr, cursor, col, E);

  for (int i = 0; i < 3; ++i){
    k_xfm<<<(N + 63)/64, 256, 0, stream>>>(h, w_l + i*4096, b_l + i*64, w_r + i*4096, b_r + i*64,
                                           xl, xr, N);
    k_gat<<<(N + 3)/4, 256, 0, stream>>>(xl, xr, h, row_ptr, col,
                                         att + i*64, b_gat + i*64, ln_g + i*64, ln_b + i*64,
                                         N, i < 2 ? 1 : 0);
  }
  k_gate<<<(N + 15)/16, 256, 0, stream>>>(h, w_g1, b_g1, w_g2, b_g2, gate, N);
  k_gmax<<<G, 256, 0, stream>>>(gate, batch, gmax, N);
  k_emb<<<(N + 255)/256, 256, 0, stream>>>(h, gate, batch, gmax, gsum, embsum, N);
  k_out<<<G, 64, 0, stream>>>(embsum, gsum, w_out, b_out, out, G);
}

// Round 7
// 540.395 us; speedup vs baseline: 2.3842x; 1.2255x over previous
//
#include <hip/hip_runtime.h>

#define NEGS   0.2f
#define LN_EPS 1e-5f
#define BSH    7          // 128 nodes per bucket
#define BN     128
#define TILE   4096       // edges per tile block

typedef const float* __restrict__ fp;

// ---------------- input transform: h = relu(x @ w_in + b_in) ----------------
__global__ __launch_bounds__(256) void k_in(fp x, fp w, fp b, float* __restrict__ h, int N){
  __shared__ float ws[24*64];
  __shared__ float bs[64];
  __shared__ float xs[4][24];
  int tid = threadIdx.x;
  for (int i = tid; i < 24*64; i += 256) ws[i] = w[i];
  if (tid < 64) bs[tid] = b[tid];
  int r = tid >> 6, c = tid & 63;
  int row = blockIdx.x*4 + r;
  if (c < 24 && row < N) xs[r][c] = x[row*24 + c];
  __syncthreads();
  if (row < N){
    float acc = bs[c];
    #pragma unroll
    for (int k = 0; k < 24; ++k) acc = fmaf(xs[r][k], ws[k*64 + c], acc);
    h[row*64 + c] = fmaxf(acc, 0.f);
  }
}

__global__ void k_zero(int* __restrict__ p, int n){
  int i = blockIdx.x*256 + threadIdx.x;
  if (i < n) p[i] = 0;
}

// ---------------- CSR build: deterministic two-level counting sort ----------------
// pass 1: per-tile per-bucket histogram (no global atomics)
__global__ __launch_bounds__(256) void t_hist(const int* __restrict__ dstA, int* __restrict__ counts,
                                              int E, int K, int ntiles){
  __shared__ int hist[512];
  int t = blockIdx.x, tid = threadIdx.x;
  for (int i = tid; i < K; i += 256) hist[i] = 0;
  __syncthreads();
  int e0 = t*TILE, e1 = min(e0 + TILE, E);
  for (int e = e0 + tid; e < e1; e += 256)
    atomicAdd(&hist[dstA[e] >> BSH], 1);
  __syncthreads();
  for (int i = tid; i < K; i += 256) counts[i*ntiles + t] = hist[i];
}

// pass 2a: exclusive scan over tiles within each bucket (ntiles <= 512)
__global__ __launch_bounds__(512) void s_scan_tiles(int* __restrict__ counts, int* __restrict__ btotal,
                                                    int ntiles){
  __shared__ int s[512];
  int b = blockIdx.x, tid = threadIdx.x;
  int v = (tid < ntiles) ? counts[b*ntiles + tid] : 0;
  s[tid] = v;
  __syncthreads();
  for (int off = 1; off < 512; off <<= 1){
    int t = (tid >= off) ? s[tid - off] : 0;
    __syncthreads();
    s[tid] += t;
    __syncthreads();
  }
  if (tid < ntiles) counts[b*ntiles + tid] = s[tid] - v;   // exclusive within bucket
  if (tid == 511) btotal[b] = s[511];
}

// pass 2b: exclusive scan over buckets (K <= 512)
__global__ __launch_bounds__(512) void s_scan_buckets(const int* __restrict__ btotal,
                                                      int* __restrict__ bbase, int K, int E){
  __shared__ int s[512];
  int tid = threadIdx.x;
  int v = (tid < K) ? btotal[tid] : 0;
  s[tid] = v;
  __syncthreads();
  for (int off = 1; off < 512; off <<= 1){
    int t = (tid >= off) ? s[tid - off] : 0;
    __syncthreads();
    s[tid] += t;
    __syncthreads();
  }
  if (tid < K) bbase[tid] = s[tid] - v;
  if (tid == 0) bbase[K] = E;
}

// pass 3: scatter edges into bucket-contiguous runs; packed = (dst_local<<25)|src
__global__ __launch_bounds__(256) void t_scatter(const int* __restrict__ srcA, const int* __restrict__ dstA,
                                                 const int* __restrict__ counts, const int* __restrict__ bbase,
                                                 unsigned* __restrict__ packed, int E, int K, int ntiles){
  __shared__ int gb[512];
  __shared__ int cur[512];
  int t = blockIdx.x, tid = threadIdx.x;
  for (int i = tid; i < K; i += 256){
    gb[i] = bbase[i] + counts[i*ntiles + t];
    cur[i] = 0;
  }
  __syncthreads();
  int e0 = t*TILE, e1 = min(e0 + TILE, E);
  for (int e = e0 + tid; e < e1; e += 256){
    int d = dstA[e], sv = srcA[e];
    int b = d >> BSH;
    int p = atomicAdd(&cur[b], 1);
    packed[gb[b] + p] = ((unsigned)(d & (BN-1)) << 25) | (unsigned)sv;
  }
}

// pass 4: per-bucket fine sort -> row_ptr + col (block-private output region)
__global__ __launch_bounds__(256) void k_fine(const unsigned* __restrict__ packed, const int* __restrict__ bbase,
                                              int* __restrict__ row_ptr, int* __restrict__ col, int N, int K){
  __shared__ int hist[BN];
  __shared__ int excl[BN];
  int b = blockIdx.x, tid = threadIdx.x;
  int node0 = b << BSH;
  int e_base = bbase[b], e_end = bbase[b+1];
  if (tid < BN) hist[tid] = 0;
  __syncthreads();
  for (int e = e_base + tid; e < e_end; e += 256)
    atomicAdd(&hist[packed[e] >> 25], 1);
  __syncthreads();
  int v = (tid < BN) ? hist[tid] : 0;
  if (tid < BN) excl[tid] = v;
  __syncthreads();
  for (int off = 1; off < BN; off <<= 1){
    int t2 = 0;
    if (tid < BN && tid >= off) t2 = excl[tid - off];
    __syncthreads();
    if (tid < BN) excl[tid] += t2;
    __syncthreads();
  }
  int nn = min(BN, N - node0);
  if (tid < nn) row_ptr[node0 + tid] = e_base + excl[tid] - v;   // exclusive
  if (b == K-1 && tid == 0) row_ptr[N] = e_end;
  if (tid < BN) hist[tid] = excl[tid] - v;                      // reuse as cursor
  __syncthreads();
  for (int e = e_base + tid; e < e_end; e += 256){
    unsigned u = packed[e];
    int dl = u >> 25;
    int p = atomicAdd(&hist[dl], 1);
    col[e_base + p] = (int)(u & 0x1FFFFFFu);
  }
}

// ---------------- per-layer transforms: xl = h@wl+bl, xr = h@wr+br ----------------
__global__ __launch_bounds__(256) void k_xfm(const float* __restrict__ h, fp wlg, fp blg, fp wrg, fp brg,
                                             float* __restrict__ xl, float* __restrict__ xr, int N){
  __shared__ float wl[4096];
  __shared__ float wr[4096];
  __shared__ float hs[64*64];
  int tid = threadIdx.x;
  for (int i = tid*4; i < 4096; i += 1024){
    *(float4*)&wl[i] = *(const float4*)&wlg[i];
    *(float4*)&wr[i] = *(const float4*)&wrg[i];
  }
  int row0 = blockIdx.x*64;
  int nrows = min(64, N - row0);
  int lim = nrows*64;
  for (int i = tid*4; i < lim; i += 1024)
    *(float4*)&hs[i] = *(const float4*)&h[(size_t)row0*64 + i];
  __syncthreads();
  int wave = tid >> 6, c = tid & 63;
  float blv = blg[c], brv = brg[c];
  float accl[16], accr[16];
  #pragma unroll
  for (int r = 0; r < 16; ++r){ accl[r] = blv; accr[r] = brv; }
  int rbase = wave*16;
  #pragma unroll 4
  for (int k = 0; k < 64; k += 4){
    float w0 = wl[k*64+c], w1 = wl[(k+1)*64+c], w2 = wl[(k+2)*64+c], w3 = wl[(k+3)*64+c];
    float v0 = wr[k*64+c], v1 = wr[(k+1)*64+c], v2 = wr[(k+2)*64+c], v3 = wr[(k+3)*64+c];
    #pragma unroll
    for (int r = 0; r < 16; ++r){
      float4 hv = *(const float4*)&hs[(rbase + r)*64 + k];
      accl[r] = fmaf(hv.x, w0, fmaf(hv.y, w1, fmaf(hv.z, w2, fmaf(hv.w, w3, accl[r]))));
      accr[r] = fmaf(hv.x, v0, fmaf(hv.y, v1, fmaf(hv.z, v2, fmaf(hv.w, v3, accr[r]))));
    }
  }
  #pragma unroll
  for (int r = 0; r < 16; ++r){
    int row = row0 + rbase + r;
    if (row < N){
      xl[(size_t)row*64 + c] = accl[r];
      xr[(size_t)row*64 + c] = accr[r];
    }
  }
}

// ---------------- fused GATv2 aggregation + residual + LayerNorm (+relu) ----------------
__global__ __launch_bounds__(256) void k_gat(const float* __restrict__ xl, const float* __restrict__ xr,
                                             float* __restrict__ h, const int* __restrict__ row_ptr,
                                             const int* __restrict__ col,
                                             fp att, fp bg, fp lng, fp lnb, int N, int do_relu){
  int lane = threadIdx.x & 63;
  int node = blockIdx.x*4 + (threadIdx.x >> 6);
  if (node >= N) return;
  float att_v = att[lane];
  size_t base = (size_t)node*64 + lane;
  float xr_v = xr[base];
  float xls  = xl[base];
  float t = xls + xr_v; t = fmaxf(t, NEGS*t);
  float p = t * att_v;
  p += __shfl_xor(p, 1); p += __shfl_xor(p, 2); p += __shfl_xor(p, 4); p += __shfl_xor(p, 8);
  const float m = p;
  int e0 = row_ptr[node], e1 = row_ptr[node+1];
  float den0 = 0.f, den1 = 0.f, den2 = 0.f, den3 = 0.f;
  float ac0 = 0.f, ac1 = 0.f, ac2 = 0.f, ac3 = 0.f;
  int e = e0;
  for (; e + 4 <= e1; e += 4){
    int j0 = col[e], j1 = col[e+1], j2 = col[e+2], j3 = col[e+3];
    float v0 = xl[(size_t)j0*64 + lane];
    float v1 = xl[(size_t)j1*64 + lane];
    float v2 = xl[(size_t)j2*64 + lane];
    float v3 = xl[(size_t)j3*64 + lane];
    float t0 = v0 + xr_v; t0 = fmaxf(t0, NEGS*t0); float s0 = t0*att_v;
    float t1 = v1 + xr_v; t1 = fmaxf(t1, NEGS*t1); float s1 = t1*att_v;
    float t2 = v2 + xr_v; t2 = fmaxf(t2, NEGS*t2); float s2 = t2*att_v;
    float t3 = v3 + xr_v; t3 = fmaxf(t3, NEGS*t3); float s3 = t3*att_v;
    s0 += __shfl_xor(s0, 1); s0 += __shfl_xor(s0, 2); s0 += __shfl_xor(s0, 4); s0 += __shfl_xor(s0, 8);
    s1 += __shfl_xor(s1, 1); s1 += __shfl_xor(s1, 2); s1 += __shfl_xor(s1, 4); s1 += __shfl_xor(s1, 8);
    s2 += __shfl_xor(s2, 1); s2 += __shfl_xor(s2, 2); s2 += __shfl_xor(s2, 4); s2 += __shfl_xor(s2, 8);
    s3 += __shfl_xor(s3, 1); s3 += __shfl_xor(s3, 2); s3 += __shfl_xor(s3, 4); s3 += __shfl_xor(s3, 8);
    float w0 = __expf(s0 - m);
    float w1 = __expf(s1 - m);
    float w2 = __expf(s2 - m);
    float w3 = __expf(s3 - m);
    den0 += w0; ac0 = fmaf(w0, v0, ac0);
    den1 += w1; ac1 = fmaf(w1, v1, ac1);
    den2 += w2; ac2 = fmaf(w2, v2, ac2);
    den3 += w3; ac3 = fmaf(w3, v3, ac3);
  }
  for (; e < e1; ++e){
    int j = col[e];
    float v = xl[(size_t)j*64 + lane];
    float tt = v + xr_v; tt = fmaxf(tt, NEGS*tt);
    float s = tt * att_v;
    s += __shfl_xor(s, 1); s += __shfl_xor(s, 2); s += __shfl_xor(s, 4); s += __shfl_xor(s, 8);
    float w = __expf(s - m);
    den0 += w; ac0 = fmaf(w, v, ac0);
  }
  float den = 1.f + ((den0 + den1) + (den2 + den3));
  float acc = xls + ((ac0 + ac1) + (ac2 + ac3));
  float o = acc/den + bg[lane] + h[base];
  float sum = o;
  #pragma unroll
  for (int off = 1; off < 64; off <<= 1) sum += __shfl_xor(sum, off);
  float mean = sum * (1.f/64.f);
  float d = o - mean;
  float vs = d*d;
  #pragma unroll
  for (int off = 1; off < 64; off <<= 1) vs += __shfl_xor(vs, off);
  float var = vs * (1.f/64.f);
  float y = d * rsqrtf(var + LN_EPS) * lng[lane] + lnb[lane];
  if (do_relu) y = fmaxf(y, 0.f);
  h[base] = y;
}

// ---------------- gate MLP ----------------
__global__ __launch_bounds__(256) void k_gate(const float* __restrict__ h, fp w1, fp b1, fp w2, fp b2,
                                              float* __restrict__ gate, int N){
  __shared__ float w1s[2048];
  __shared__ float hrow[16][64];
  int tid = threadIdx.x;
  for (int i = tid*4; i < 2048; i += 1024) *(float4*)&w1s[i] = *(const float4*)&w1[i];
  int base = blockIdx.x*16;
  int nrows = min(16, N - base);
  int lim = nrows*64;
  for (int i = tid*4; i < lim; i += 1024)
    *(float4*)&hrow[0][i] = *(const float4*)&h[(size_t)base*64 + i];
  __syncthreads();
  int wave = tid >> 6, lane = tid & 63;
  int j = lane & 31, half = lane >> 5;
  float b1v = b1[j], w2v = w2[j], b2v = b2[0];
  int k0 = half*32;
  #pragma unroll
  for (int it = 0; it < 4; ++it){
    int r = wave*4 + it;
    int node = base + r;
    if (node >= N) break;
    float s = 0.f;
    #pragma unroll 8
    for (int k = k0; k < k0 + 32; ++k) s = fmaf(hrow[r][k], w1s[k*32 + j], s);
    s += __shfl_xor(s, 32);
    float hid = fmaxf(s + b1v, 0.f);
    float contrib = (half == 0) ? hid * w2v : 0.f;
    #pragma unroll
    for (int off = 1; off < 64; off <<= 1) contrib += __shfl_xor(contrib, off);
    if (lane == 0) gate[node] = contrib + b2v;
  }
}

// ---------------- per-graph gate max ----------------
__global__ __launch_bounds__(256) void k_gmax(const float* __restrict__ gate, const int* __restrict__ batch,
                                              float* __restrict__ gmax, int N){
  int g = blockIdx.x, tid = threadIdx.x;
  int lo = 0, hi = N;
  while (lo < hi){ int mid = (lo + hi) >> 1; if (batch[mid] < g) lo = mid + 1; else hi = mid; }
  int start = lo;
  hi = N;
  while (lo < hi){ int mid = (lo + hi) >> 1; if (batch[mid] < g + 1) lo = mid + 1; else hi = mid; }
  int end = lo;
  float m = -3.4e38f;
  for (int i = start + tid; i < end; i += 256) m = fmaxf(m, gate[i]);
  #pragma unroll
  for (int off = 1; off < 64; off <<= 1) m = fmaxf(m, __shfl_xor(m, off));
  __shared__ float ws[4];
  if ((tid & 63) == 0) ws[tid >> 6] = m;
  __syncthreads();
  if (tid == 0) gmax[g] = fmaxf(fmaxf(ws[0], ws[1]), fmaxf(ws[2], ws[3]));
}

// ---------------- pooling accumulate ----------------
__global__ __launch_bounds__(256) void k_emb(const float* __restrict__ h, const float* __restrict__ gate,
                                             const int* __restrict__ batch, const float* __restrict__ gmax,
                                             float* __restrict__ gsum, float* __restrict__ embsum, int N){
  int lane = threadIdx.x & 63;
  int wv = blockIdx.x*4 + (threadIdx.x >> 6);
  int s = wv*64;
  if (s >= N) return;
  int e = min(s + 64, N);
  int cur = batch[s];
  float gm = gmax[cur];
  float acc = 0.f, asum = 0.f;
  for (int i = s; i < e; ++i){
    int g = batch[i];
    if (g != cur){
      atomicAdd(&embsum[cur*64 + lane], acc);
      if (lane == 0) atomicAdd(&gsum[cur], asum);
      acc = 0.f; asum = 0.f; cur = g; gm = gmax[g];
    }
    float a = __expf(gate[i] - gm);
    acc = fmaf(a, h[(size_t)i*64 + lane], acc);
    asum += a;
  }
  atomicAdd(&embsum[cur*64 + lane], acc);
  if (lane == 0) atomicAdd(&gsum[cur], asum);
}

// ---------------- final GEMM ----------------
__global__ __launch_bounds__(64) void k_out(const float* __restrict__ embsum, const float* __restrict__ gsum,
                                            fp w_out, fp b_out, float* __restrict__ out, int G){
  int g = blockIdx.x, lane = threadIdx.x;
  __shared__ float emb[64];
  float gs = gsum[g];
  float inv = (gs > 0.f) ? 1.f/gs : 1.f;
  emb[lane] = embsum[g*64 + lane] * inv;
  __syncthreads();
  float o2 = b_out[lane];
  #pragma unroll 8
  for (int d = 0; d < 64; ++d) o2 = fmaf(emb[d], w_out[d*64 + lane], o2);
  out[g*64 + lane] = fmaxf(o2, 0.f);
}

extern "C" void kernel_launch(void* const* d_in, const int* in_sizes, int n_in,
                              void* d_out, int out_size, void* d_ws, size_t ws_size,
                              hipStream_t stream) {
  const int N = in_sizes[0] / 24;
  const int E = in_sizes[1] / 2;
  const int G = out_size / 64;
  const int K = (N + BN - 1) >> BSH;          // buckets
  const int ntiles = (E + TILE - 1) / TILE;   // edge tiles (<=512)

  fp x      = (fp)d_in[0];
  const int* edge  = (const int*)d_in[1];
  const int* batch = (const int*)d_in[2];
  fp w_in   = (fp)d_in[3];
  fp b_in   = (fp)d_in[4];
  fp w_l    = (fp)d_in[5];
  fp b_l    = (fp)d_in[6];
  fp w_r    = (fp)d_in[7];
  fp b_r    = (fp)d_in[8];
  fp att    = (fp)d_in[9];
  fp b_gat  = (fp)d_in[10];
  fp ln_g   = (fp)d_in[11];
  fp ln_b   = (fp)d_in[12];
  fp w_g1   = (fp)d_in[13];
  fp b_g1   = (fp)d_in[14];
  fp w_g2   = (fp)d_in[15];
  fp b_g2   = (fp)d_in[16];
  fp w_out  = (fp)d_in[17];
  fp b_out  = (fp)d_in[18];
  float* out = (float*)d_out;

  char* wp = (char*)d_ws;
  auto alloc = [&](size_t bytes) -> char* {
    char* p = wp; wp += (bytes + 255) & ~(size_t)255; return p;
  };
  float*    h       = (float*)   alloc((size_t)N*64*sizeof(float));
  float*    xl      = (float*)   alloc((size_t)N*64*sizeof(float));
  float*    xr      = (float*)   alloc((size_t)N*64*sizeof(float));
  int*      col     = (int*)     alloc((size_t)E*sizeof(int));
  unsigned* packed  = (unsigned*)alloc((size_t)E*sizeof(unsigned));
  int*      counts  = (int*)     alloc((size_t)K*ntiles*sizeof(int));
  int*      btotal  = (int*)     alloc((size_t)K*sizeof(int));
  int*      bbase   = (int*)     alloc((size_t)(K+1)*sizeof(int));
  int*      row_ptr = (int*)     alloc((size_t)(N+1)*sizeof(int));
  float*    gate    = (float*)   alloc((size_t)N*sizeof(float));
  float*    gmax    = (float*)   alloc((size_t)G*sizeof(float));
  int poolN = G + G*64;
  float*    gsum    = (float*)   alloc((size_t)poolN*sizeof(float));
  float*    embsum  = gsum + G;

  const int* srcA = edge;
  const int* dstA = edge + E;

  k_in<<<(N + 3)/4, 256, 0, stream>>>(x, w_in, b_in, h, N);
  k_zero<<<(poolN + 255)/256, 256, 0, stream>>>((int*)gsum, poolN);

  t_hist<<<ntiles, 256, 0, stream>>>(dstA, counts, E, K, ntiles);
  s_scan_tiles<<<K, 512, 0, stream>>>(counts, btotal, ntiles);
  s_scan_buckets<<<1, 512, 0, stream>>>(btotal, bbase, K, E);
  t_scatter<<<ntiles, 256, 0, stream>>>(srcA, dstA, counts, bbase, packed, E, K, ntiles);
  k_fine<<<K, 256, 0, stream>>>(packed, bbase, row_ptr, col, N, K);

  for (int i = 0; i < 3; ++i){
    k_xfm<<<(N + 63)/64, 256, 0, stream>>>(h, w_l + i*4096, b_l + i*64, w_r + i*4096, b_r + i*64,
                                           xl, xr, N);
    k_gat<<<(N + 3)/4, 256, 0, stream>>>(xl, xr, h, row_ptr, col,
                                         att + i*64, b_gat + i*64, ln_g + i*64, ln_b + i*64,
                                         N, i < 2 ? 1 : 0);
  }
  k_gate<<<(N + 15)/16, 256, 0, stream>>>(h, w_g1, b_g1, w_g2, b_g2, gate, N);
  k_gmax<<<G, 256, 0, stream>>>(gate, batch, gmax, N);
  k_emb<<<(N + 255)/256, 256, 0, stream>>>(h, gate, batch, gmax, gsum, embsum, N);
  k_out<<<G, 64, 0, stream>>>(embsum, gsum, w_out, b_out, out, G);
}

// Round 8
// 496.389 us; speedup vs baseline: 2.5956x; 1.0887x over previous
//
#include <hip/hip_runtime.h>

#define NEGS   0.2f
#define LN_EPS 1e-5f
#define BSH    7          // 128 nodes per bucket
#define BN     128
#define TILE   4096       // edges per tile block
#define LOG2E  1.44269504f

typedef const float* __restrict__ fp;

// pure-VALU 16-lane sum: quad_perm xor1, xor2, then row_ror 4, 8 (row = 16 lanes)
template<int CTRL>
__device__ __forceinline__ float dppadd(float x){
  int y = __builtin_amdgcn_update_dpp(0, __float_as_int(x), CTRL, 0xF, 0xF, true);
  return x + __int_as_float(y);
}
__device__ __forceinline__ float hsum16(float s){
  s = dppadd<0xB1>(s);    // quad_perm [1,0,3,2] : xor 1
  s = dppadd<0x4E>(s);    // quad_perm [2,3,0,1] : xor 2
  s = dppadd<0x124>(s);   // row_ror:4
  s = dppadd<0x128>(s);   // row_ror:8
  return s;
}

// ---------------- input transform: h = relu(x @ w_in + b_in) ----------------
__global__ __launch_bounds__(256) void k_in(fp x, fp w, fp b, float* __restrict__ h, int N){
  __shared__ float ws[24*64];
  __shared__ float bs[64];
  __shared__ float xs[4][24];
  int tid = threadIdx.x;
  for (int i = tid; i < 24*64; i += 256) ws[i] = w[i];
  if (tid < 64) bs[tid] = b[tid];
  int r = tid >> 6, c = tid & 63;
  int row = blockIdx.x*4 + r;
  if (c < 24 && row < N) xs[r][c] = x[row*24 + c];
  __syncthreads();
  if (row < N){
    float acc = bs[c];
    #pragma unroll
    for (int k = 0; k < 24; ++k) acc = fmaf(xs[r][k], ws[k*64 + c], acc);
    h[row*64 + c] = fmaxf(acc, 0.f);
  }
}

__global__ void k_zero(int* __restrict__ p, int n){
  int i = blockIdx.x*256 + threadIdx.x;
  if (i < n) p[i] = 0;
}

// ---------------- CSR build: deterministic two-level counting sort ----------------
__global__ __launch_bounds__(256) void t_hist(const int* __restrict__ dstA, int* __restrict__ counts,
                                              int E, int K, int ntiles){
  __shared__ int hist[512];
  int t = blockIdx.x, tid = threadIdx.x;
  for (int i = tid; i < K; i += 256) hist[i] = 0;
  __syncthreads();
  int e0 = t*TILE, e1 = min(e0 + TILE, E);
  for (int e = e0 + tid; e < e1; e += 256)
    atomicAdd(&hist[dstA[e] >> BSH], 1);
  __syncthreads();
  for (int i = tid; i < K; i += 256) counts[i*ntiles + t] = hist[i];
}

__global__ __launch_bounds__(512) void s_scan_tiles(int* __restrict__ counts, int* __restrict__ btotal,
                                                    int ntiles){
  __shared__ int s[512];
  int b = blockIdx.x, tid = threadIdx.x;
  int v = (tid < ntiles) ? counts[b*ntiles + tid] : 0;
  s[tid] = v;
  __syncthreads();
  for (int off = 1; off < 512; off <<= 1){
    int t = (tid >= off) ? s[tid - off] : 0;
    __syncthreads();
    s[tid] += t;
    __syncthreads();
  }
  if (tid < ntiles) counts[b*ntiles + tid] = s[tid] - v;
  if (tid == 511) btotal[b] = s[511];
}

__global__ __launch_bounds__(512) void s_scan_buckets(const int* __restrict__ btotal,
                                                      int* __restrict__ bbase, int K, int E){
  __shared__ int s[512];
  int tid = threadIdx.x;
  int v = (tid < K) ? btotal[tid] : 0;
  s[tid] = v;
  __syncthreads();
  for (int off = 1; off < 512; off <<= 1){
    int t = (tid >= off) ? s[tid - off] : 0;
    __syncthreads();
    s[tid] += t;
    __syncthreads();
  }
  if (tid < K) bbase[tid] = s[tid] - v;
  if (tid == 0) bbase[K] = E;
}

__global__ __launch_bounds__(256) void t_scatter(const int* __restrict__ srcA, const int* __restrict__ dstA,
                                                 const int* __restrict__ counts, const int* __restrict__ bbase,
                                                 unsigned* __restrict__ packed, int E, int K, int ntiles){
  __shared__ int gb[512];
  __shared__ int cur[512];
  int t = blockIdx.x, tid = threadIdx.x;
  for (int i = tid; i < K; i += 256){
    gb[i] = bbase[i] + counts[i*ntiles + t];
    cur[i] = 0;
  }
  __syncthreads();
  int e0 = t*TILE, e1 = min(e0 + TILE, E);
  for (int e = e0 + tid; e < e1; e += 256){
    int d = dstA[e], sv = srcA[e];
    int b = d >> BSH;
    int p = atomicAdd(&cur[b], 1);
    packed[gb[b] + p] = ((unsigned)(d & (BN-1)) << 25) | (unsigned)sv;
  }
}

__global__ __launch_bounds__(256) void k_fine(const unsigned* __restrict__ packed, const int* __restrict__ bbase,
                                              int* __restrict__ row_ptr, int* __restrict__ col, int N, int K){
  __shared__ int hist[BN];
  __shared__ int excl[BN];
  int b = blockIdx.x, tid = threadIdx.x;
  int node0 = b << BSH;
  int e_base = bbase[b], e_end = bbase[b+1];
  if (tid < BN) hist[tid] = 0;
  __syncthreads();
  for (int e = e_base + tid; e < e_end; e += 256)
    atomicAdd(&hist[packed[e] >> 25], 1);
  __syncthreads();
  int v = (tid < BN) ? hist[tid] : 0;
  if (tid < BN) excl[tid] = v;
  __syncthreads();
  for (int off = 1; off < BN; off <<= 1){
    int t2 = 0;
    if (tid < BN && tid >= off) t2 = excl[tid - off];
    __syncthreads();
    if (tid < BN) excl[tid] += t2;
    __syncthreads();
  }
  int nn = min(BN, N - node0);
  if (tid < nn) row_ptr[node0 + tid] = e_base + excl[tid] - v;
  if (b == K-1 && tid == 0) row_ptr[N] = e_end;
  if (tid < BN) hist[tid] = excl[tid] - v;
  __syncthreads();
  for (int e = e_base + tid; e < e_end; e += 256){
    unsigned u = packed[e];
    int dl = u >> 25;
    int p = atomicAdd(&hist[dl], 1);
    col[e_base + p] = (int)(u & 0x1FFFFFFu);
  }
}

// ---------------- per-layer transforms: xl = h@wl+bl, xr = h@wr+br ----------------
__global__ __launch_bounds__(256) void k_xfm(const float* __restrict__ h, fp wlg, fp blg, fp wrg, fp brg,
                                             float* __restrict__ xl, float* __restrict__ xr, int N){
  __shared__ float wl[4096];
  __shared__ float wr[4096];
  __shared__ float hs[64*64];
  int tid = threadIdx.x;
  for (int i = tid*4; i < 4096; i += 1024){
    *(float4*)&wl[i] = *(const float4*)&wlg[i];
    *(float4*)&wr[i] = *(const float4*)&wrg[i];
  }
  int row0 = blockIdx.x*64;
  int nrows = min(64, N - row0);
  int lim = nrows*64;
  for (int i = tid*4; i < lim; i += 1024)
    *(float4*)&hs[i] = *(const float4*)&h[(size_t)row0*64 + i];
  __syncthreads();
  int wave = tid >> 6, c = tid & 63;
  float blv = blg[c], brv = brg[c];
  float accl[16], accr[16];
  #pragma unroll
  for (int r = 0; r < 16; ++r){ accl[r] = blv; accr[r] = brv; }
  int rbase = wave*16;
  #pragma unroll 4
  for (int k = 0; k < 64; k += 4){
    float w0 = wl[k*64+c], w1 = wl[(k+1)*64+c], w2 = wl[(k+2)*64+c], w3 = wl[(k+3)*64+c];
    float v0 = wr[k*64+c], v1 = wr[(k+1)*64+c], v2 = wr[(k+2)*64+c], v3 = wr[(k+3)*64+c];
    #pragma unroll
    for (int r = 0; r < 16; ++r){
      float4 hv = *(const float4*)&hs[(rbase + r)*64 + k];
      accl[r] = fmaf(hv.x, w0, fmaf(hv.y, w1, fmaf(hv.z, w2, fmaf(hv.w, w3, accl[r]))));
      accr[r] = fmaf(hv.x, v0, fmaf(hv.y, v1, fmaf(hv.z, v2, fmaf(hv.w, v3, accr[r]))));
    }
  }
  #pragma unroll
  for (int r = 0; r < 16; ++r){
    int row = row0 + rbase + r;
    if (row < N){
      xl[(size_t)row*64 + c] = accl[r];
      xr[(size_t)row*64 + c] = accr[r];
    }
  }
}

// ---------------- fused GATv2 aggregation + residual + LayerNorm (+relu) ----------------
// att pre-scaled by log2(e): score sums live in log2 domain, weight = exp2(s-m) = v_exp.
// 16-lane head reductions via pure-VALU DPP butterfly (no LDS pipe in hot loop).
__global__ __launch_bounds__(256) void k_gat(const float* __restrict__ xl, const float* __restrict__ xr,
                                             float* __restrict__ h, const int* __restrict__ row_ptr,
                                             const int* __restrict__ col,
                                             fp att, fp bg, fp lng, fp lnb, int N, int do_relu){
  int lane = threadIdx.x & 63;
  int node = blockIdx.x*4 + (threadIdx.x >> 6);
  if (node >= N) return;
  float att_v = att[lane] * LOG2E;
  size_t base = (size_t)node*64 + lane;
  float xr_v = xr[base];
  float xls  = xl[base];
  float t = xls + xr_v; t = fmaxf(t, NEGS*t);
  const float m = hsum16(t * att_v);     // self-loop score (log2 domain) = softmax shift
  int e0 = row_ptr[node], e1 = row_ptr[node+1];
  float den0 = 0.f, den1 = 0.f, den2 = 0.f, den3 = 0.f;
  float ac0 = 0.f, ac1 = 0.f, ac2 = 0.f, ac3 = 0.f;
  int e = e0;
  for (; e + 4 <= e1; e += 4){
    int j0 = col[e], j1 = col[e+1], j2 = col[e+2], j3 = col[e+3];
    float v0 = xl[(size_t)j0*64 + lane];
    float v1 = xl[(size_t)j1*64 + lane];
    float v2 = xl[(size_t)j2*64 + lane];
    float v3 = xl[(size_t)j3*64 + lane];
    float t0 = v0 + xr_v; t0 = fmaxf(t0, NEGS*t0);
    float t1 = v1 + xr_v; t1 = fmaxf(t1, NEGS*t1);
    float t2 = v2 + xr_v; t2 = fmaxf(t2, NEGS*t2);
    float t3 = v3 + xr_v; t3 = fmaxf(t3, NEGS*t3);
    float s0 = hsum16(t0 * att_v);
    float s1 = hsum16(t1 * att_v);
    float s2 = hsum16(t2 * att_v);
    float s3 = hsum16(t3 * att_v);
    float w0 = __builtin_amdgcn_exp2f(s0 - m);
    float w1 = __builtin_amdgcn_exp2f(s1 - m);
    float w2 = __builtin_amdgcn_exp2f(s2 - m);
    float w3 = __builtin_amdgcn_exp2f(s3 - m);
    den0 += w0; ac0 = fmaf(w0, v0, ac0);
    den1 += w1; ac1 = fmaf(w1, v1, ac1);
    den2 += w2; ac2 = fmaf(w2, v2, ac2);
    den3 += w3; ac3 = fmaf(w3, v3, ac3);
  }
  for (; e < e1; ++e){
    int j = col[e];
    float v = xl[(size_t)j*64 + lane];
    float tt = v + xr_v; tt = fmaxf(tt, NEGS*tt);
    float s = hsum16(tt * att_v);
    float w = __builtin_amdgcn_exp2f(s - m);
    den0 += w; ac0 = fmaf(w, v, ac0);
  }
  float den = 1.f + ((den0 + den1) + (den2 + den3));   // self-loop: exp2(0)=1
  float acc = xls + ((ac0 + ac1) + (ac2 + ac3));
  float o = acc/den + bg[lane] + h[base];
  float sum = o;
  #pragma unroll
  for (int off = 1; off < 64; off <<= 1) sum += __shfl_xor(sum, off);
  float mean = sum * (1.f/64.f);
  float d = o - mean;
  float vs = d*d;
  #pragma unroll
  for (int off = 1; off < 64; off <<= 1) vs += __shfl_xor(vs, off);
  float var = vs * (1.f/64.f);
  float y = d * rsqrtf(var + LN_EPS) * lng[lane] + lnb[lane];
  if (do_relu) y = fmaxf(y, 0.f);
  h[base] = y;
}

// ---------------- gate MLP ----------------
__global__ __launch_bounds__(256) void k_gate(const float* __restrict__ h, fp w1, fp b1, fp w2, fp b2,
                                              float* __restrict__ gate, int N){
  __shared__ float w1s[2048];
  __shared__ float hrow[16][64];
  int tid = threadIdx.x;
  for (int i = tid*4; i < 2048; i += 1024) *(float4*)&w1s[i] = *(const float4*)&w1[i];
  int base = blockIdx.x*16;
  int nrows = min(16, N - base);
  int lim = nrows*64;
  for (int i = tid*4; i < lim; i += 1024)
    *(float4*)&hrow[0][i] = *(const float4*)&h[(size_t)base*64 + i];
  __syncthreads();
  int wave = tid >> 6, lane = tid & 63;
  int j = lane & 31, half = lane >> 5;
  float b1v = b1[j], w2v = w2[j], b2v = b2[0];
  int k0 = half*32;
  #pragma unroll
  for (int it = 0; it < 4; ++it){
    int r = wave*4 + it;
    int node = base + r;
    if (node >= N) break;
    float s = 0.f;
    #pragma unroll 8
    for (int k = k0; k < k0 + 32; ++k) s = fmaf(hrow[r][k], w1s[k*32 + j], s);
    s += __shfl_xor(s, 32);
    float hid = fmaxf(s + b1v, 0.f);
    float contrib = (half == 0) ? hid * w2v : 0.f;
    #pragma unroll
    for (int off = 1; off < 64; off <<= 1) contrib += __shfl_xor(contrib, off);
    if (lane == 0) gate[node] = contrib + b2v;
  }
}

// ---------------- per-graph gate max ----------------
__global__ __launch_bounds__(256) void k_gmax(const float* __restrict__ gate, const int* __restrict__ batch,
                                              float* __restrict__ gmax, int N){
  int g = blockIdx.x, tid = threadIdx.x;
  int lo = 0, hi = N;
  while (lo < hi){ int mid = (lo + hi) >> 1; if (batch[mid] < g) lo = mid + 1; else hi = mid; }
  int start = lo;
  hi = N;
  while (lo < hi){ int mid = (lo + hi) >> 1; if (batch[mid] < g + 1) lo = mid + 1; else hi = mid; }
  int end = lo;
  float m = -3.4e38f;
  for (int i = start + tid; i < end; i += 256) m = fmaxf(m, gate[i]);
  #pragma unroll
  for (int off = 1; off < 64; off <<= 1) m = fmaxf(m, __shfl_xor(m, off));
  __shared__ float ws[4];
  if ((tid & 63) == 0) ws[tid >> 6] = m;
  __syncthreads();
  if (tid == 0) gmax[g] = fmaxf(fmaxf(ws[0], ws[1]), fmaxf(ws[2], ws[3]));
}

// ---------------- pooling accumulate ----------------
__global__ __launch_bounds__(256) void k_emb(const float* __restrict__ h, const float* __restrict__ gate,
                                             const int* __restrict__ batch, const float* __restrict__ gmax,
                                             float* __restrict__ gsum, float* __restrict__ embsum, int N){
  int lane = threadIdx.x & 63;
  int wv = blockIdx.x*4 + (threadIdx.x >> 6);
  int s = wv*64;
  if (s >= N) return;
  int e = min(s + 64, N);
  int cur = batch[s];
  float gm = gmax[cur];
  float acc = 0.f, asum = 0.f;
  for (int i = s; i < e; ++i){
    int g = batch[i];
    if (g != cur){
      atomicAdd(&embsum[cur*64 + lane], acc);
      if (lane == 0) atomicAdd(&gsum[cur], asum);
      acc = 0.f; asum = 0.f; cur = g; gm = gmax[g];
    }
    float a = __expf(gate[i] - gm);
    acc = fmaf(a, h[(size_t)i*64 + lane], acc);
    asum += a;
  }
  atomicAdd(&embsum[cur*64 + lane], acc);
  if (lane == 0) atomicAdd(&gsum[cur], asum);
}

// ---------------- final GEMM ----------------
__global__ __launch_bounds__(64) void k_out(const float* __restrict__ embsum, const float* __restrict__ gsum,
                                            fp w_out, fp b_out, float* __restrict__ out, int G){
  int g = blockIdx.x, lane = threadIdx.x;
  __shared__ float emb[64];
  float gs = gsum[g];
  float inv = (gs > 0.f) ? 1.f/gs : 1.f;
  emb[lane] = embsum[g*64 + lane] * inv;
  __syncthreads();
  float o2 = b_out[lane];
  #pragma unroll 8
  for (int d = 0; d < 64; ++d) o2 = fmaf(emb[d], w_out[d*64 + lane], o2);
  out[g*64 + lane] = fmaxf(o2, 0.f);
}

extern "C" void kernel_launch(void* const* d_in, const int* in_sizes, int n_in,
                              void* d_out, int out_size, void* d_ws, size_t ws_size,
                              hipStream_t stream) {
  const int N = in_sizes[0] / 24;
  const int E = in_sizes[1] / 2;
  const int G = out_size / 64;
  const int K = (N + BN - 1) >> BSH;
  const int ntiles = (E + TILE - 1) / TILE;

  fp x      = (fp)d_in[0];
  const int* edge  = (const int*)d_in[1];
  const int* batch = (const int*)d_in[2];
  fp w_in   = (fp)d_in[3];
  fp b_in   = (fp)d_in[4];
  fp w_l    = (fp)d_in[5];
  fp b_l    = (fp)d_in[6];
  fp w_r    = (fp)d_in[7];
  fp b_r    = (fp)d_in[8];
  fp att    = (fp)d_in[9];
  fp b_gat  = (fp)d_in[10];
  fp ln_g   = (fp)d_in[11];
  fp ln_b   = (fp)d_in[12];
  fp w_g1   = (fp)d_in[13];
  fp b_g1   = (fp)d_in[14];
  fp w_g2   = (fp)d_in[15];
  fp b_g2   = (fp)d_in[16];
  fp w_out  = (fp)d_in[17];
  fp b_out  = (fp)d_in[18];
  float* out = (float*)d_out;

  char* wp = (char*)d_ws;
  auto alloc = [&](size_t bytes) -> char* {
    char* p = wp; wp += (bytes + 255) & ~(size_t)255; return p;
  };
  float*    h       = (float*)   alloc((size_t)N*64*sizeof(float));
  float*    xl      = (float*)   alloc((size_t)N*64*sizeof(float));
  float*    xr      = (float*)   alloc((size_t)N*64*sizeof(float));
  int*      col     = (int*)     alloc((size_t)E*sizeof(int));
  unsigned* packed  = (unsigned*)alloc((size_t)E*sizeof(unsigned));
  int*      counts  = (int*)     alloc((size_t)K*ntiles*sizeof(int));
  int*      btotal  = (int*)     alloc((size_t)K*sizeof(int));
  int*      bbase   = (int*)     alloc((size_t)(K+1)*sizeof(int));
  int*      row_ptr = (int*)     alloc((size_t)(N+1)*sizeof(int));
  float*    gate    = (float*)   alloc((size_t)N*sizeof(float));
  float*    gmax    = (float*)   alloc((size_t)G*sizeof(float));
  int poolN = G + G*64;
  float*    gsum    = (float*)   alloc((size_t)poolN*sizeof(float));
  float*    embsum  = gsum + G;

  const int* srcA = edge;
  const int* dstA = edge + E;

  k_in<<<(N + 3)/4, 256, 0, stream>>>(x, w_in, b_in, h, N);
  k_zero<<<(poolN + 255)/256, 256, 0, stream>>>((int*)gsum, poolN);

  t_hist<<<ntiles, 256, 0, stream>>>(dstA, counts, E, K, ntiles);
  s_scan_tiles<<<K, 512, 0, stream>>>(counts, btotal, ntiles);
  s_scan_buckets<<<1, 512, 0, stream>>>(btotal, bbase, K, E);
  t_scatter<<<ntiles, 256, 0, stream>>>(srcA, dstA, counts, bbase, packed, E, K, ntiles);
  k_fine<<<K, 256, 0, stream>>>(packed, bbase, row_ptr, col, N, K);

  for (int i = 0; i < 3; ++i){
    k_xfm<<<(N + 63)/64, 256, 0, stream>>>(h, w_l + i*4096, b_l + i*64, w_r + i*4096, b_r + i*64,
                                           xl, xr, N);
    k_gat<<<(N + 3)/4, 256, 0, stream>>>(xl, xr, h, row_ptr, col,
                                         att + i*64, b_gat + i*64, ln_g + i*64, ln_b + i*64,
                                         N, i < 2 ? 1 : 0);
  }
  k_gate<<<(N + 15)/16, 256, 0, stream>>>(h, w_g1, b_g1, w_g2, b_g2, gate, N);
  k_gmax<<<G, 256, 0, stream>>>(gate, batch, gmax, N);
  k_emb<<<(N + 255)/256, 256, 0, stream>>>(h, gate, batch, gmax, gsum, embsum, N);
  k_out<<<G, 64, 0, stream>>>(embsum, gsum, w_out, b_out, out, G);
}

// Round 9
// 471.897 us; speedup vs baseline: 2.7303x; 1.0519x over previous
//
#include <hip/hip_runtime.h>

#define NEGS   0.2f
#define LN_EPS 1e-5f
#define BSH    7          // 128 nodes per bucket
#define BN     128
#define TILE   4096       // edges per tile block
#define LOG2E  1.44269504f

typedef const float* __restrict__ fp;
typedef _Float16 v2h __attribute__((ext_vector_type(2)));

__device__ __forceinline__ v2h u2h(unsigned u){ union{unsigned u; v2h h;} c; c.u = u; return c.h; }
__device__ __forceinline__ unsigned h2u(v2h h){ union{v2h h; unsigned u;} c; c.h = h; return c.u; }

// pure-VALU quad butterflies + xor-4 swizzle: sum over each 8-lane group
template<int CTRL>
__device__ __forceinline__ float dppadd(float x){
  int y = __builtin_amdgcn_update_dpp(0, __float_as_int(x), CTRL, 0xF, 0xF, true);
  return x + __int_as_float(y);
}
__device__ __forceinline__ float hsum8(float s){
  s = dppadd<0xB1>(s);    // quad_perm xor 1
  s = dppadd<0x4E>(s);    // quad_perm xor 2
  s += __shfl_xor(s, 4);  // cross-quad within 8-lane group
  return s;
}

// ---------------- input transform: h = relu(x @ w_in + b_in) ----------------
__global__ __launch_bounds__(256) void k_in(fp x, fp w, fp b, float* __restrict__ h, int N){
  __shared__ float ws[24*64];
  __shared__ float bs[64];
  __shared__ float xs[4][24];
  int tid = threadIdx.x;
  for (int i = tid; i < 24*64; i += 256) ws[i] = w[i];
  if (tid < 64) bs[tid] = b[tid];
  int r = tid >> 6, c = tid & 63;
  int row = blockIdx.x*4 + r;
  if (c < 24 && row < N) xs[r][c] = x[row*24 + c];
  __syncthreads();
  if (row < N){
    float acc = bs[c];
    #pragma unroll
    for (int k = 0; k < 24; ++k) acc = fmaf(xs[r][k], ws[k*64 + c], acc);
    h[row*64 + c] = fmaxf(acc, 0.f);
  }
}

__global__ void k_zero(int* __restrict__ p, int n){
  int i = blockIdx.x*256 + threadIdx.x;
  if (i < n) p[i] = 0;
}

// ---------------- CSR build: deterministic two-level counting sort ----------------
__global__ __launch_bounds__(256) void t_hist(const int* __restrict__ dstA, int* __restrict__ counts,
                                              int E, int K, int ntiles){
  __shared__ int hist[512];
  int t = blockIdx.x, tid = threadIdx.x;
  for (int i = tid; i < K; i += 256) hist[i] = 0;
  __syncthreads();
  int e0 = t*TILE, e1 = min(e0 + TILE, E);
  for (int e = e0 + tid; e < e1; e += 256)
    atomicAdd(&hist[dstA[e] >> BSH], 1);
  __syncthreads();
  for (int i = tid; i < K; i += 256) counts[i*ntiles + t] = hist[i];
}

__global__ __launch_bounds__(512) void s_scan_tiles(int* __restrict__ counts, int* __restrict__ btotal,
                                                    int ntiles){
  __shared__ int s[512];
  int b = blockIdx.x, tid = threadIdx.x;
  int v = (tid < ntiles) ? counts[b*ntiles + tid] : 0;
  s[tid] = v;
  __syncthreads();
  for (int off = 1; off < 512; off <<= 1){
    int t = (tid >= off) ? s[tid - off] : 0;
    __syncthreads();
    s[tid] += t;
    __syncthreads();
  }
  if (tid < ntiles) counts[b*ntiles + tid] = s[tid] - v;
  if (tid == 511) btotal[b] = s[511];
}

__global__ __launch_bounds__(512) void s_scan_buckets(const int* __restrict__ btotal,
                                                      int* __restrict__ bbase, int K, int E){
  __shared__ int s[512];
  int tid = threadIdx.x;
  int v = (tid < K) ? btotal[tid] : 0;
  s[tid] = v;
  __syncthreads();
  for (int off = 1; off < 512; off <<= 1){
    int t = (tid >= off) ? s[tid - off] : 0;
    __syncthreads();
    s[tid] += t;
    __syncthreads();
  }
  if (tid < K) bbase[tid] = s[tid] - v;
  if (tid == 0) bbase[K] = E;
}

__global__ __launch_bounds__(256) void t_scatter(const int* __restrict__ srcA, const int* __restrict__ dstA,
                                                 const int* __restrict__ counts, const int* __restrict__ bbase,
                                                 unsigned* __restrict__ packed, int E, int K, int ntiles){
  __shared__ int gb[512];
  __shared__ int cur[512];
  int t = blockIdx.x, tid = threadIdx.x;
  for (int i = tid; i < K; i += 256){
    gb[i] = bbase[i] + counts[i*ntiles + t];
    cur[i] = 0;
  }
  __syncthreads();
  int e0 = t*TILE, e1 = min(e0 + TILE, E);
  for (int e = e0 + tid; e < e1; e += 256){
    int d = dstA[e], sv = srcA[e];
    int b = d >> BSH;
    int p = atomicAdd(&cur[b], 1);
    packed[gb[b] + p] = ((unsigned)(d & (BN-1)) << 25) | (unsigned)sv;
  }
}

__global__ __launch_bounds__(256) void k_fine(const unsigned* __restrict__ packed, const int* __restrict__ bbase,
                                              int* __restrict__ row_ptr, int* __restrict__ col, int N, int K){
  __shared__ int hist[BN];
  __shared__ int excl[BN];
  int b = blockIdx.x, tid = threadIdx.x;
  int node0 = b << BSH;
  int e_base = bbase[b], e_end = bbase[b+1];
  if (tid < BN) hist[tid] = 0;
  __syncthreads();
  for (int e = e_base + tid; e < e_end; e += 256)
    atomicAdd(&hist[packed[e] >> 25], 1);
  __syncthreads();
  int v = (tid < BN) ? hist[tid] : 0;
  if (tid < BN) excl[tid] = v;
  __syncthreads();
  for (int off = 1; off < BN; off <<= 1){
    int t2 = 0;
    if (tid < BN && tid >= off) t2 = excl[tid - off];
    __syncthreads();
    if (tid < BN) excl[tid] += t2;
    __syncthreads();
  }
  int nn = min(BN, N - node0);
  if (tid < nn) row_ptr[node0 + tid] = e_base + excl[tid] - v;
  if (b == K-1 && tid == 0) row_ptr[N] = e_end;
  if (tid < BN) hist[tid] = excl[tid] - v;
  __syncthreads();
  for (int e = e_base + tid; e < e_end; e += 256){
    unsigned u = packed[e];
    int dl = u >> 25;
    int p = atomicAdd(&hist[dl], 1);
    col[e_base + p] = (int)(u & 0x1FFFFFFu);
  }
}

// ---------------- per-layer transforms: xl16/xr16 = packed-f16 (h@wl+bl, h@wr+br) ----------------
__global__ __launch_bounds__(256) void k_xfm(const float* __restrict__ h, fp wlg, fp blg, fp wrg, fp brg,
                                             unsigned* __restrict__ xl16, unsigned* __restrict__ xr16, int N){
  __shared__ float wl[4096];
  __shared__ float wr[4096];
  __shared__ float hs[64*64];
  int tid = threadIdx.x;
  for (int i = tid*4; i < 4096; i += 1024){
    *(float4*)&wl[i] = *(const float4*)&wlg[i];
    *(float4*)&wr[i] = *(const float4*)&wrg[i];
  }
  int row0 = blockIdx.x*64;
  int nrows = min(64, N - row0);
  int lim = nrows*64;
  for (int i = tid*4; i < lim; i += 1024)
    *(float4*)&hs[i] = *(const float4*)&h[(size_t)row0*64 + i];
  __syncthreads();
  int wave = tid >> 6, c = tid & 63;
  float blv = blg[c], brv = brg[c];
  float accl[16], accr[16];
  #pragma unroll
  for (int r = 0; r < 16; ++r){ accl[r] = blv; accr[r] = brv; }
  int rbase = wave*16;
  #pragma unroll 4
  for (int k = 0; k < 64; k += 4){
    float w0 = wl[k*64+c], w1 = wl[(k+1)*64+c], w2 = wl[(k+2)*64+c], w3 = wl[(k+3)*64+c];
    float v0 = wr[k*64+c], v1 = wr[(k+1)*64+c], v2 = wr[(k+2)*64+c], v3 = wr[(k+3)*64+c];
    #pragma unroll
    for (int r = 0; r < 16; ++r){
      float4 hv = *(const float4*)&hs[(rbase + r)*64 + k];
      accl[r] = fmaf(hv.x, w0, fmaf(hv.y, w1, fmaf(hv.z, w2, fmaf(hv.w, w3, accl[r]))));
      accr[r] = fmaf(hv.x, v0, fmaf(hv.y, v1, fmaf(hv.z, v2, fmaf(hv.w, v3, accr[r]))));
    }
  }
  #pragma unroll
  for (int r = 0; r < 16; ++r){
    int row = row0 + rbase + r;
    float ahi = __shfl_down(accl[r], 1);
    float bhi = __shfl_down(accr[r], 1);
    if (row < N && !(c & 1)){
      v2h pa; pa.x = (_Float16)accl[r]; pa.y = (_Float16)ahi;
      v2h pb; pb.x = (_Float16)accr[r]; pb.y = (_Float16)bhi;
      xl16[(size_t)row*32 + (c >> 1)] = h2u(pa);
      xr16[(size_t)row*32 + (c >> 1)] = h2u(pb);
    }
  }
}

// ---------------- fused GATv2 aggregation + residual + LayerNorm (+relu) ----------------
// xl/xr packed f16 (2 features/lane, 32 lanes/row). Wave processes 2 edges at once
// (lower/upper 32 lanes). Score via v_dot2_f32_f16 + 8-lane DPP reduce, log2 domain.
__global__ __launch_bounds__(256) void k_gat(const unsigned* __restrict__ xl16, const unsigned* __restrict__ xr16,
                                             float* __restrict__ h, const int* __restrict__ row_ptr,
                                             const int* __restrict__ col,
                                             fp att, fp bg, fp lng, fp lnb, int N, int do_relu){
  int lane = threadIdx.x & 63;
  int node = blockIdx.x*4 + (threadIdx.x >> 6);
  if (node >= N) return;
  int l = lane & 31;
  bool lower = lane < 32;
  v2h att2; att2.x = (_Float16)(att[2*l] * LOG2E); att2.y = (_Float16)(att[2*l+1] * LOG2E);
  v2h xrv = u2h(xr16[(size_t)node*32 + l]);
  v2h xlv = u2h(xl16[(size_t)node*32 + l]);
  // self-loop score = softmax shift (identical in both halves)
  v2h ts = xlv + xrv;
  ts = __builtin_elementwise_max(ts, ts * (_Float16)NEGS);
  const float m = hsum8(__builtin_amdgcn_fdot2(ts, att2, 0.f, false));
  float den0 = lower ? 1.f : 0.f, den1 = 0.f;
  float2 acc0, acc1;
  acc0.x = lower ? (float)xlv.x : 0.f;
  acc0.y = lower ? (float)xlv.y : 0.f;
  acc1.x = 0.f; acc1.y = 0.f;
  int e = row_ptr[node], e1 = row_ptr[node+1];
  for (; e + 4 <= e1; e += 4){
    int ja0 = col[e],   jb0 = col[e+1];
    int ja1 = col[e+2], jb1 = col[e+3];
    int j0 = lower ? ja0 : jb0;
    int j1 = lower ? ja1 : jb1;
    unsigned u0 = xl16[(size_t)j0*32 + l];
    unsigned u1 = xl16[(size_t)j1*32 + l];
    v2h v0 = u2h(u0), v1 = u2h(u1);
    v2h t0 = v0 + xrv; t0 = __builtin_elementwise_max(t0, t0 * (_Float16)NEGS);
    v2h t1 = v1 + xrv; t1 = __builtin_elementwise_max(t1, t1 * (_Float16)NEGS);
    float s0 = hsum8(__builtin_amdgcn_fdot2(t0, att2, 0.f, false));
    float s1 = hsum8(__builtin_amdgcn_fdot2(t1, att2, 0.f, false));
    float w0 = __builtin_amdgcn_exp2f(s0 - m);
    float w1 = __builtin_amdgcn_exp2f(s1 - m);
    den0 += w0; den1 += w1;
    acc0.x = fmaf(w0, (float)v0.x, acc0.x); acc0.y = fmaf(w0, (float)v0.y, acc0.y);
    acc1.x = fmaf(w1, (float)v1.x, acc1.x); acc1.y = fmaf(w1, (float)v1.y, acc1.y);
  }
  for (; e + 2 <= e1; e += 2){
    int ja = col[e], jb = col[e+1];
    int j0 = lower ? ja : jb;
    v2h v0 = u2h(xl16[(size_t)j0*32 + l]);
    v2h t0 = v0 + xrv; t0 = __builtin_elementwise_max(t0, t0 * (_Float16)NEGS);
    float s0 = hsum8(__builtin_amdgcn_fdot2(t0, att2, 0.f, false));
    float w0 = __builtin_amdgcn_exp2f(s0 - m);
    den0 += w0;
    acc0.x = fmaf(w0, (float)v0.x, acc0.x); acc0.y = fmaf(w0, (float)v0.y, acc0.y);
  }
  if (e < e1){
    int ja = col[e];
    v2h v0 = u2h(xl16[(size_t)ja*32 + l]);
    v2h t0 = v0 + xrv; t0 = __builtin_elementwise_max(t0, t0 * (_Float16)NEGS);
    float s0 = hsum8(__builtin_amdgcn_fdot2(t0, att2, 0.f, false));
    float w0 = __builtin_amdgcn_exp2f(s0 - m);
    if (!lower) w0 = 0.f;                         // avoid double-count on odd tail
    den0 += w0;
    acc0.x = fmaf(w0, (float)v0.x, acc0.x); acc0.y = fmaf(w0, (float)v0.y, acc0.y);
  }
  float den = den0 + den1;
  float2 acc; acc.x = acc0.x + acc1.x; acc.y = acc0.y + acc1.y;
  den   += __shfl_xor(den, 32);
  acc.x += __shfl_xor(acc.x, 32);
  acc.y += __shfl_xor(acc.y, 32);
  float inv = 1.f / den;
  float2 bg2 = *(const float2*)&bg[2*l];
  float2 h2  = *(const float2*)&h[(size_t)node*64 + 2*l];
  float2 o2;
  o2.x = acc.x*inv + bg2.x + h2.x;
  o2.y = acc.y*inv + bg2.y + h2.y;
  // LayerNorm over 64 features (pairs in 32 lanes; halves duplicated)
  float sl = o2.x + o2.y;
  #pragma unroll
  for (int off = 1; off < 32; off <<= 1) sl += __shfl_xor(sl, off);
  float mean = sl * (1.f/64.f);
  float dx = o2.x - mean, dy = o2.y - mean;
  float vsl = dx*dx + dy*dy;
  #pragma unroll
  for (int off = 1; off < 32; off <<= 1) vsl += __shfl_xor(vsl, off);
  float rs = rsqrtf(vsl * (1.f/64.f) + LN_EPS);
  float2 lg2 = *(const float2*)&lng[2*l];
  float2 lb2 = *(const float2*)&lnb[2*l];
  float yx = dx*rs*lg2.x + lb2.x;
  float yy = dy*rs*lg2.y + lb2.y;
  if (do_relu){ yx = fmaxf(yx, 0.f); yy = fmaxf(yy, 0.f); }
  if (lower){
    float2 y2; y2.x = yx; y2.y = yy;
    *(float2*)&h[(size_t)node*64 + 2*l] = y2;
  }
}

// ---------------- gate MLP ----------------
__global__ __launch_bounds__(256) void k_gate(const float* __restrict__ h, fp w1, fp b1, fp w2, fp b2,
                                              float* __restrict__ gate, int N){
  __shared__ float w1s[2048];
  __shared__ float hrow[16][64];
  int tid = threadIdx.x;
  for (int i = tid*4; i < 2048; i += 1024) *(float4*)&w1s[i] = *(const float4*)&w1[i];
  int base = blockIdx.x*16;
  int nrows = min(16, N - base);
  int lim = nrows*64;
  for (int i = tid*4; i < lim; i += 1024)
    *(float4*)&hrow[0][i] = *(const float4*)&h[(size_t)base*64 + i];
  __syncthreads();
  int wave = tid >> 6, lane = tid & 63;
  int j = lane & 31, half = lane >> 5;
  float b1v = b1[j], w2v = w2[j], b2v = b2[0];
  int k0 = half*32;
  #pragma unroll
  for (int it = 0; it < 4; ++it){
    int r = wave*4 + it;
    int node = base + r;
    if (node >= N) break;
    float s = 0.f;
    #pragma unroll 8
    for (int k = k0; k < k0 + 32; ++k) s = fmaf(hrow[r][k], w1s[k*32 + j], s);
    s += __shfl_xor(s, 32);
    float hid = fmaxf(s + b1v, 0.f);
    float contrib = (half == 0) ? hid * w2v : 0.f;
    #pragma unroll
    for (int off = 1; off < 64; off <<= 1) contrib += __shfl_xor(contrib, off);
    if (lane == 0) gate[node] = contrib + b2v;
  }
}

// ---------------- per-graph gate max ----------------
__global__ __launch_bounds__(256) void k_gmax(const float* __restrict__ gate, const int* __restrict__ batch,
                                              float* __restrict__ gmax, int N){
  int g = blockIdx.x, tid = threadIdx.x;
  int lo = 0, hi = N;
  while (lo < hi){ int mid = (lo + hi) >> 1; if (batch[mid] < g) lo = mid + 1; else hi = mid; }
  int start = lo;
  hi = N;
  while (lo < hi){ int mid = (lo + hi) >> 1; if (batch[mid] < g + 1) lo = mid + 1; else hi = mid; }
  int end = lo;
  float m = -3.4e38f;
  for (int i = start + tid; i < end; i += 256) m = fmaxf(m, gate[i]);
  #pragma unroll
  for (int off = 1; off < 64; off <<= 1) m = fmaxf(m, __shfl_xor(m, off));
  __shared__ float ws[4];
  if ((tid & 63) == 0) ws[tid >> 6] = m;
  __syncthreads();
  if (tid == 0) gmax[g] = fmaxf(fmaxf(ws[0], ws[1]), fmaxf(ws[2], ws[3]));
}

// ---------------- pooling accumulate ----------------
__global__ __launch_bounds__(256) void k_emb(const float* __restrict__ h, const float* __restrict__ gate,
                                             const int* __restrict__ batch, const float* __restrict__ gmax,
                                             float* __restrict__ gsum, float* __restrict__ embsum, int N){
  int lane = threadIdx.x & 63;
  int wv = blockIdx.x*4 + (threadIdx.x >> 6);
  int s = wv*64;
  if (s >= N) return;
  int e = min(s + 64, N);
  int cur = batch[s];
  float gm = gmax[cur];
  float acc = 0.f, asum = 0.f;
  for (int i = s; i < e; ++i){
    int g = batch[i];
    if (g != cur){
      atomicAdd(&embsum[cur*64 + lane], acc);
      if (lane == 0) atomicAdd(&gsum[cur], asum);
      acc = 0.f; asum = 0.f; cur = g; gm = gmax[g];
    }
    float a = __expf(gate[i] - gm);
    acc = fmaf(a, h[(size_t)i*64 + lane], acc);
    asum += a;
  }
  atomicAdd(&embsum[cur*64 + lane], acc);
  if (lane == 0) atomicAdd(&gsum[cur], asum);
}

// ---------------- final GEMM ----------------
__global__ __launch_bounds__(64) void k_out(const float* __restrict__ embsum, const float* __restrict__ gsum,
                                            fp w_out, fp b_out, float* __restrict__ out, int G){
  int g = blockIdx.x, lane = threadIdx.x;
  __shared__ float emb[64];
  float gs = gsum[g];
  float inv = (gs > 0.f) ? 1.f/gs : 1.f;
  emb[lane] = embsum[g*64 + lane] * inv;
  __syncthreads();
  float o2 = b_out[lane];
  #pragma unroll 8
  for (int d = 0; d < 64; ++d) o2 = fmaf(emb[d], w_out[d*64 + lane], o2);
  out[g*64 + lane] = fmaxf(o2, 0.f);
}

extern "C" void kernel_launch(void* const* d_in, const int* in_sizes, int n_in,
                              void* d_out, int out_size, void* d_ws, size_t ws_size,
                              hipStream_t stream) {
  const int N = in_sizes[0] / 24;
  const int E = in_sizes[1] / 2;
  const int G = out_size / 64;
  const int K = (N + BN - 1) >> BSH;
  const int ntiles = (E + TILE - 1) / TILE;

  fp x      = (fp)d_in[0];
  const int* edge  = (const int*)d_in[1];
  const int* batch = (const int*)d_in[2];
  fp w_in   = (fp)d_in[3];
  fp b_in   = (fp)d_in[4];
  fp w_l    = (fp)d_in[5];
  fp b_l    = (fp)d_in[6];
  fp w_r    = (fp)d_in[7];
  fp b_r    = (fp)d_in[8];
  fp att    = (fp)d_in[9];
  fp b_gat  = (fp)d_in[10];
  fp ln_g   = (fp)d_in[11];
  fp ln_b   = (fp)d_in[12];
  fp w_g1   = (fp)d_in[13];
  fp b_g1   = (fp)d_in[14];
  fp w_g2   = (fp)d_in[15];
  fp b_g2   = (fp)d_in[16];
  fp w_out  = (fp)d_in[17];
  fp b_out  = (fp)d_in[18];
  float* out = (float*)d_out;

  char* wp = (char*)d_ws;
  auto alloc = [&](size_t bytes) -> char* {
    char* p = wp; wp += (bytes + 255) & ~(size_t)255; return p;
  };
  float*    h       = (float*)   alloc((size_t)N*64*sizeof(float));
  unsigned* xl16    = (unsigned*)alloc((size_t)N*32*sizeof(unsigned));
  unsigned* xr16    = (unsigned*)alloc((size_t)N*32*sizeof(unsigned));
  int*      col     = (int*)     alloc((size_t)E*sizeof(int));
  unsigned* packed  = (unsigned*)alloc((size_t)E*sizeof(unsigned));
  int*      counts  = (int*)     alloc((size_t)K*ntiles*sizeof(int));
  int*      btotal  = (int*)     alloc((size_t)K*sizeof(int));
  int*      bbase   = (int*)     alloc((size_t)(K+1)*sizeof(int));
  int*      row_ptr = (int*)     alloc((size_t)(N+1)*sizeof(int));
  float*    gate    = (float*)   alloc((size_t)N*sizeof(float));
  float*    gmax    = (float*)   alloc((size_t)G*sizeof(float));
  int poolN = G + G*64;
  float*    gsum    = (float*)   alloc((size_t)poolN*sizeof(float));
  float*    embsum  = gsum + G;

  const int* srcA = edge;
  const int* dstA = edge + E;

  k_in<<<(N + 3)/4, 256, 0, stream>>>(x, w_in, b_in, h, N);
  k_zero<<<(poolN + 255)/256, 256, 0, stream>>>((int*)gsum, poolN);

  t_hist<<<ntiles, 256, 0, stream>>>(dstA, counts, E, K, ntiles);
  s_scan_tiles<<<K, 512, 0, stream>>>(counts, btotal, ntiles);
  s_scan_buckets<<<1, 512, 0, stream>>>(btotal, bbase, K, E);
  t_scatter<<<ntiles, 256, 0, stream>>>(srcA, dstA, counts, bbase, packed, E, K, ntiles);
  k_fine<<<K, 256, 0, stream>>>(packed, bbase, row_ptr, col, N, K);

  for (int i = 0; i < 3; ++i){
    k_xfm<<<(N + 63)/64, 256, 0, stream>>>(h, w_l + i*4096, b_l + i*64, w_r + i*4096, b_r + i*64,
                                           xl16, xr16, N);
    k_gat<<<(N + 3)/4, 256, 0, stream>>>(xl16, xr16, h, row_ptr, col,
                                         att + i*64, b_gat + i*64, ln_g + i*64, ln_b + i*64,
                                         N, i < 2 ? 1 : 0);
  }
  k_gate<<<(N + 15)/16, 256, 0, stream>>>(h, w_g1, b_g1, w_g2, b_g2, gate, N);
  k_gmax<<<G, 256, 0, stream>>>(gate, batch, gmax, N);
  k_emb<<<(N + 255)/256, 256, 0, stream>>>(h, gate, batch, gmax, gsum, embsum, N);
  k_out<<<G, 64, 0, stream>>>(embsum, gsum, w_out, b_out, out, G);
}

// Round 12
// 437.373 us; speedup vs baseline: 2.9458x; 1.0789x over previous
//
#include <hip/hip_runtime.h>

#define NEGS   0.2f
#define LN_EPS 1e-5f
#define BSH    7          // 128 nodes per bucket
#define BN     128
#define TILE   4096       // edges per tile block
#define LOG2E  1.44269504f

typedef const float* __restrict__ fp;
typedef _Float16 v2h __attribute__((ext_vector_type(2)));

__device__ __forceinline__ v2h u2h(unsigned u){ union{unsigned u; v2h h;} c; c.u = u; return c.h; }
__device__ __forceinline__ unsigned h2u(v2h h){ union{v2h h; unsigned u;} c; c.h = h; return c.u; }

// pure-VALU quad butterflies + xor-4 shuffle: sum over each 8-lane group
template<int CTRL>
__device__ __forceinline__ float dppadd(float x){
  int y = __builtin_amdgcn_update_dpp(0, __float_as_int(x), CTRL, 0xF, 0xF, true);
  return x + __int_as_float(y);
}
__device__ __forceinline__ float hsum8(float s){
  s = dppadd<0xB1>(s);    // quad_perm xor 1
  s = dppadd<0x4E>(s);    // quad_perm xor 2
  s += __shfl_xor(s, 4);  // cross-quad within 8-lane group
  return s;
}
// edge softmax weight in log2 domain (att pre-scaled by log2 e)
__device__ __forceinline__ float edge_w(v2h v, v2h xrv, v2h att2, float m){
  v2h t = v + xrv;
  t = __builtin_elementwise_max(t, t * (_Float16)NEGS);
  float s = hsum8(__builtin_amdgcn_fdot2(t, att2, 0.f, false));
  return __builtin_amdgcn_exp2f(s - m);
}

// ---------------- input transform: h = relu(x @ w_in + b_in) ----------------
__global__ __launch_bounds__(256) void k_in(fp x, fp w, fp b, float* __restrict__ h, int N){
  __shared__ float ws[24*64];
  __shared__ float bs[64];
  __shared__ float xs[4][24];
  int tid = threadIdx.x;
  for (int i = tid; i < 24*64; i += 256) ws[i] = w[i];
  if (tid < 64) bs[tid] = b[tid];
  int r = tid >> 6, c = tid & 63;
  int row = blockIdx.x*4 + r;
  if (c < 24 && row < N) xs[r][c] = x[row*24 + c];
  __syncthreads();
  if (row < N){
    float acc = bs[c];
    #pragma unroll
    for (int k = 0; k < 24; ++k) acc = fmaf(xs[r][k], ws[k*64 + c], acc);
    h[row*64 + c] = fmaxf(acc, 0.f);
  }
}

// ---------------- CSR build: deterministic two-level counting sort ----------------
__global__ __launch_bounds__(256) void t_hist(const int* __restrict__ dstA, int* __restrict__ counts,
                                              int E, int K, int ntiles){
  __shared__ int hist[512];
  int t = blockIdx.x, tid = threadIdx.x;
  for (int i = tid; i < K; i += 256) hist[i] = 0;
  __syncthreads();
  int e0 = t*TILE, e1 = min(e0 + TILE, E);
  for (int e = e0 + tid; e < e1; e += 256)
    atomicAdd(&hist[dstA[e] >> BSH], 1);
  __syncthreads();
  for (int i = tid; i < K; i += 256) counts[i*ntiles + t] = hist[i];
}

__global__ __launch_bounds__(512) void s_scan_tiles(int* __restrict__ counts, int* __restrict__ btotal,
                                                    int ntiles){
  __shared__ int s[512];
  int b = blockIdx.x, tid = threadIdx.x;
  int v = (tid < ntiles) ? counts[b*ntiles + tid] : 0;
  s[tid] = v;
  __syncthreads();
  for (int off = 1; off < 512; off <<= 1){
    int t = (tid >= off) ? s[tid - off] : 0;
    __syncthreads();
    s[tid] += t;
    __syncthreads();
  }
  if (tid < ntiles) counts[b*ntiles + tid] = s[tid] - v;
  if (tid == 511) btotal[b] = s[511];
}

__global__ __launch_bounds__(512) void s_scan_buckets(const int* __restrict__ btotal,
                                                      int* __restrict__ bbase, int K, int E){
  __shared__ int s[512];
  int tid = threadIdx.x;
  int v = (tid < K) ? btotal[tid] : 0;
  s[tid] = v;
  __syncthreads();
  for (int off = 1; off < 512; off <<= 1){
    int t = (tid >= off) ? s[tid - off] : 0;
    __syncthreads();
    s[tid] += t;
    __syncthreads();
  }
  if (tid < K) bbase[tid] = s[tid] - v;
  if (tid == 0) bbase[K] = E;
}

__global__ __launch_bounds__(256) void t_scatter(const int* __restrict__ srcA, const int* __restrict__ dstA,
                                                 const int* __restrict__ counts, const int* __restrict__ bbase,
                                                 unsigned* __restrict__ packed, int E, int K, int ntiles){
  __shared__ int gb[512];
  __shared__ int cur[512];
  int t = blockIdx.x, tid = threadIdx.x;
  for (int i = tid; i < K; i += 256){
    gb[i] = bbase[i] + counts[i*ntiles + t];
    cur[i] = 0;
  }
  __syncthreads();
  int e0 = t*TILE, e1 = min(e0 + TILE, E);
  for (int e = e0 + tid; e < e1; e += 256){
    int d = dstA[e], sv = srcA[e];
    int b = d >> BSH;
    int p = atomicAdd(&cur[b], 1);
    packed[gb[b] + p] = ((unsigned)(d & (BN-1)) << 25) | (unsigned)sv;
  }
}

__global__ __launch_bounds__(256) void k_fine(const unsigned* __restrict__ packed, const int* __restrict__ bbase,
                                              int* __restrict__ row_ptr, int* __restrict__ col, int N, int K){
  __shared__ int hist[BN];
  __shared__ int excl[BN];
  int b = blockIdx.x, tid = threadIdx.x;
  int node0 = b << BSH;
  int e_base = bbase[b], e_end = bbase[b+1];
  if (tid < BN) hist[tid] = 0;
  __syncthreads();
  for (int e = e_base + tid; e < e_end; e += 256)
    atomicAdd(&hist[packed[e] >> 25], 1);
  __syncthreads();
  int v = (tid < BN) ? hist[tid] : 0;
  if (tid < BN) excl[tid] = v;
  __syncthreads();
  for (int off = 1; off < BN; off <<= 1){
    int t2 = 0;
    if (tid < BN && tid >= off) t2 = excl[tid - off];
    __syncthreads();
    if (tid < BN) excl[tid] += t2;
    __syncthreads();
  }
  int nn = min(BN, N - node0);
  if (tid < nn) row_ptr[node0 + tid] = e_base + excl[tid] - v;
  if (b == K-1 && tid == 0) row_ptr[N] = e_end;
  if (tid < BN) hist[tid] = excl[tid] - v;
  __syncthreads();
  for (int e = e_base + tid; e < e_end; e += 256){
    unsigned u = packed[e];
    int dl = u >> 25;
    int p = atomicAdd(&hist[dl], 1);
    col[e_base + p] = (int)(u & 0x1FFFFFFu);
  }
}

// ---------------- per-layer transforms: xl16/xr16 = packed-f16 (h@wl+bl, h@wr+br) ----------------
__global__ __launch_bounds__(256) void k_xfm(const float* __restrict__ h, fp wlg, fp blg, fp wrg, fp brg,
                                             unsigned* __restrict__ xl16, unsigned* __restrict__ xr16, int N){
  __shared__ float wl[4096];
  __shared__ float wr[4096];
  __shared__ float hs[64*64];
  int tid = threadIdx.x;
  for (int i = tid*4; i < 4096; i += 1024){
    *(float4*)&wl[i] = *(const float4*)&wlg[i];
    *(float4*)&wr[i] = *(const float4*)&wrg[i];
  }
  int row0 = blockIdx.x*64;
  int nrows = min(64, N - row0);
  int lim = nrows*64;
  for (int i = tid*4; i < lim; i += 1024)
    *(float4*)&hs[i] = *(const float4*)&h[(size_t)row0*64 + i];
  __syncthreads();
  int wave = tid >> 6, c = tid & 63;
  float blv = blg[c], brv = brg[c];
  float accl[16], accr[16];
  #pragma unroll
  for (int r = 0; r < 16; ++r){ accl[r] = blv; accr[r] = brv; }
  int rbase = wave*16;
  #pragma unroll 4
  for (int k = 0; k < 64; k += 4){
    float w0 = wl[k*64+c], w1 = wl[(k+1)*64+c], w2 = wl[(k+2)*64+c], w3 = wl[(k+3)*64+c];
    float v0 = wr[k*64+c], v1 = wr[(k+1)*64+c], v2 = wr[(k+2)*64+c], v3 = wr[(k+3)*64+c];
    #pragma unroll
    for (int r = 0; r < 16; ++r){
      float4 hv = *(const float4*)&hs[(rbase + r)*64 + k];
      accl[r] = fmaf(hv.x, w0, fmaf(hv.y, w1, fmaf(hv.z, w2, fmaf(hv.w, w3, accl[r]))));
      accr[r] = fmaf(hv.x, v0, fmaf(hv.y, v1, fmaf(hv.z, v2, fmaf(hv.w, v3, accr[r]))));
    }
  }
  #pragma unroll
  for (int r = 0; r < 16; ++r){
    int row = row0 + rbase + r;
    float ahi = __shfl_down(accl[r], 1);
    float bhi = __shfl_down(accr[r], 1);
    if (row < N && !(c & 1)){
      v2h pa; pa.x = (_Float16)accl[r]; pa.y = (_Float16)ahi;
      v2h pb; pb.x = (_Float16)accr[r]; pb.y = (_Float16)bhi;
      xl16[(size_t)row*32 + (c >> 1)] = h2u(pa);
      xr16[(size_t)row*32 + (c >> 1)] = h2u(pb);
    }
  }
}

// ---------------- fused GATv2 aggregation + residual + LayerNorm (+relu) ----------------
// xl/xr packed f16 (2 features/lane, 32 lanes/row). Wave processes 2 edges at once
// (lower/upper 32-lane halves); 8-edge unroll = 4 independent gathers in flight.
__global__ __launch_bounds__(256) void k_gat(const unsigned* __restrict__ xl16, const unsigned* __restrict__ xr16,
                                             float* __restrict__ h, const int* __restrict__ row_ptr,
                                             const int* __restrict__ col,
                                             fp att, fp bg, fp lng, fp lnb, int N, int do_relu){
  int lane = threadIdx.x & 63;
  int node = blockIdx.x*4 + (threadIdx.x >> 6);
  if (node >= N) return;
  int l = lane & 31;
  bool lower = lane < 32;
  int off = lower ? 0 : 1;
  v2h att2; att2.x = (_Float16)(att[2*l] * LOG2E); att2.y = (_Float16)(att[2*l+1] * LOG2E);
  v2h xrv = u2h(xr16[(size_t)node*32 + l]);
  v2h xlv = u2h(xl16[(size_t)node*32 + l]);
  // self-loop score = softmax shift (identical in both halves)
  v2h ts = xlv + xrv;
  ts = __builtin_elementwise_max(ts, ts * (_Float16)NEGS);
  const float m = hsum8(__builtin_amdgcn_fdot2(ts, att2, 0.f, false));
  float den0 = lower ? 1.f : 0.f, den1 = 0.f, den2 = 0.f, den3 = 0.f;
  float a0x = lower ? (float)xlv.x : 0.f, a0y = lower ? (float)xlv.y : 0.f;
  float a1x = 0.f, a1y = 0.f, a2x = 0.f, a2y = 0.f, a3x = 0.f, a3y = 0.f;
  int e = row_ptr[node], e1 = row_ptr[node+1];
  for (; e + 8 <= e1; e += 8){
    int j0 = col[e+off], j1 = col[e+2+off], j2 = col[e+4+off], j3 = col[e+6+off];
    v2h v0 = u2h(xl16[(size_t)j0*32 + l]);
    v2h v1 = u2h(xl16[(size_t)j1*32 + l]);
    v2h v2 = u2h(xl16[(size_t)j2*32 + l]);
    v2h v3 = u2h(xl16[(size_t)j3*32 + l]);
    float w0 = edge_w(v0, xrv, att2, m);
    float w1 = edge_w(v1, xrv, att2, m);
    float w2 = edge_w(v2, xrv, att2, m);
    float w3 = edge_w(v3, xrv, att2, m);
    den0 += w0; a0x = fmaf(w0, (float)v0.x, a0x); a0y = fmaf(w0, (float)v0.y, a0y);
    den1 += w1; a1x = fmaf(w1, (float)v1.x, a1x); a1y = fmaf(w1, (float)v1.y, a1y);
    den2 += w2; a2x = fmaf(w2, (float)v2.x, a2x); a2y = fmaf(w2, (float)v2.y, a2y);
    den3 += w3; a3x = fmaf(w3, (float)v3.x, a3x); a3y = fmaf(w3, (float)v3.y, a3y);
  }
  for (; e + 2 <= e1; e += 2){
    int j0 = col[e+off];
    v2h v0 = u2h(xl16[(size_t)j0*32 + l]);
    float w0 = edge_w(v0, xrv, att2, m);
    den0 += w0; a0x = fmaf(w0, (float)v0.x, a0x); a0y = fmaf(w0, (float)v0.y, a0y);
  }
  if (e < e1){
    int j0 = col[e];
    v2h v0 = u2h(xl16[(size_t)j0*32 + l]);
    float w0 = edge_w(v0, xrv, att2, m);
    if (!lower) w0 = 0.f;                         // avoid double-count on odd tail
    den0 += w0; a0x = fmaf(w0, (float)v0.x, a0x); a0y = fmaf(w0, (float)v0.y, a0y);
  }
  float den = (den0 + den1) + (den2 + den3);
  float ax = (a0x + a1x) + (a2x + a3x);
  float ay = (a0y + a1y) + (a2y + a3y);
  den += __shfl_xor(den, 32);
  ax  += __shfl_xor(ax, 32);
  ay  += __shfl_xor(ay, 32);
  float inv = 1.f / den;
  float2 bg2 = *(const float2*)&bg[2*l];
  float2 h2  = *(const float2*)&h[(size_t)node*64 + 2*l];
  float ox = ax*inv + bg2.x + h2.x;
  float oy = ay*inv + bg2.y + h2.y;
  // LayerNorm over 64 features (pairs in 32 lanes; halves duplicated)
  float sl = ox + oy;
  #pragma unroll
  for (int o = 1; o < 32; o <<= 1) sl += __shfl_xor(sl, o);
  float mean = sl * (1.f/64.f);
  float dx = ox - mean, dy = oy - mean;
  float vsl = dx*dx + dy*dy;
  #pragma unroll
  for (int o = 1; o < 32; o <<= 1) vsl += __shfl_xor(vsl, o);
  float rs = rsqrtf(vsl * (1.f/64.f) + LN_EPS);
  float2 lg2 = *(const float2*)&lng[2*l];
  float2 lb2 = *(const float2*)&lnb[2*l];
  float yx = dx*rs*lg2.x + lb2.x;
  float yy = dy*rs*lg2.y + lb2.y;
  if (do_relu){ yx = fmaxf(yx, 0.f); yy = fmaxf(yy, 0.f); }
  if (lower){
    float2 y2; y2.x = yx; y2.y = yy;
    *(float2*)&h[(size_t)node*64 + 2*l] = y2;
  }
}

// ---------------- gate MLP ----------------
__global__ __launch_bounds__(256) void k_gate(const float* __restrict__ h, fp w1, fp b1, fp w2, fp b2,
                                              float* __restrict__ gate, int N){
  __shared__ float w1s[2048];
  __shared__ float hrow[16][64];
  int tid = threadIdx.x;
  for (int i = tid*4; i < 2048; i += 1024) *(float4*)&w1s[i] = *(const float4*)&w1[i];
  int base = blockIdx.x*16;
  int nrows = min(16, N - base);
  int lim = nrows*64;
  for (int i = tid*4; i < lim; i += 1024)
    *(float4*)&hrow[0][i] = *(const float4*)&h[(size_t)base*64 + i];
  __syncthreads();
  int wave = tid >> 6, lane = tid & 63;
  int j = lane & 31, half = lane >> 5;
  float b1v = b1[j], w2v = w2[j], b2v = b2[0];
  int k0 = half*32;
  #pragma unroll
  for (int it = 0; it < 4; ++it){
    int r = wave*4 + it;
    int node = base + r;
    if (node >= N) break;
    float s = 0.f;
    #pragma unroll 8
    for (int k = k0; k < k0 + 32; ++k) s = fmaf(hrow[r][k], w1s[k*32 + j], s);
    s += __shfl_xor(s, 32);
    float hid = fmaxf(s + b1v, 0.f);
    float contrib = (half == 0) ? hid * w2v : 0.f;
    #pragma unroll
    for (int o = 1; o < 64; o <<= 1) contrib += __shfl_xor(contrib, o);
    if (lane == 0) gate[node] = contrib + b2v;
  }
}

// ---------------- per-graph gate max + zero pool accumulators ----------------
__global__ __launch_bounds__(256) void k_gmax(const float* __restrict__ gate, const int* __restrict__ batch,
                                              float* __restrict__ gmax, float* __restrict__ gsum,
                                              float* __restrict__ embsum, int N){
  int g = blockIdx.x, tid = threadIdx.x;
  // zero this graph's accumulators (k_emb runs strictly after this dispatch)
  if (tid < 64) embsum[g*64 + tid] = 0.f;
  if (tid == 64) gsum[g] = 0.f;
  int lo = 0, hi = N;
  while (lo < hi){ int mid = (lo + hi) >> 1; if (batch[mid] < g) lo = mid + 1; else hi = mid; }
  int start = lo;
  hi = N;
  while (lo < hi){ int mid = (lo + hi) >> 1; if (batch[mid] < g + 1) lo = mid + 1; else hi = mid; }
  int end = lo;
  float m = -3.4e38f;
  for (int i = start + tid; i < end; i += 256) m = fmaxf(m, gate[i]);
  #pragma unroll
  for (int o = 1; o < 64; o <<= 1) m = fmaxf(m, __shfl_xor(m, o));
  __shared__ float ws[4];
  if ((tid & 63) == 0) ws[tid >> 6] = m;
  __syncthreads();
  if (tid == 0) gmax[g] = fmaxf(fmaxf(ws[0], ws[1]), fmaxf(ws[2], ws[3]));
}

// ---------------- pooling accumulate ----------------
__global__ __launch_bounds__(256) void k_emb(const float* __restrict__ h, const float* __restrict__ gate,
                                             const int* __restrict__ batch, const float* __restrict__ gmax,
                                             float* __restrict__ gsum, float* __restrict__ embsum, int N){
  int lane = threadIdx.x & 63;
  int wv = blockIdx.x*4 + (threadIdx.x >> 6);
  int s = wv*64;
  if (s >= N) return;
  int e = min(s + 64, N);
  int cur = batch[s];
  float gm = gmax[cur];
  float acc = 0.f, asum = 0.f;
  for (int i = s; i < e; ++i){
    int g = batch[i];
    if (g != cur){
      atomicAdd(&embsum[cur*64 + lane], acc);
      if (lane == 0) atomicAdd(&gsum[cur], asum);
      acc = 0.f; asum = 0.f; cur = g; gm = gmax[g];
    }
    float a = __expf(gate[i] - gm);
    acc = fmaf(a, h[(size_t)i*64 + lane], acc);
    asum += a;
  }
  atomicAdd(&embsum[cur*64 + lane], acc);
  if (lane == 0) atomicAdd(&gsum[cur], asum);
}

// ---------------- final GEMM ----------------
__global__ __launch_bounds__(64) void k_out(const float* __restrict__ embsum, const float* __restrict__ gsum,
                                            fp w_out, fp b_out, float* __restrict__ out, int G){
  int g = blockIdx.x, lane = threadIdx.x;
  __shared__ float emb[64];
  float gs = gsum[g];
  float inv = (gs > 0.f) ? 1.f/gs : 1.f;
  emb[lane] = embsum[g*64 + lane] * inv;
  __syncthreads();
  float o2 = b_out[lane];
  #pragma unroll 8
  for (int d = 0; d < 64; ++d) o2 = fmaf(emb[d], w_out[d*64 + lane], o2);
  out[g*64 + lane] = fmaxf(o2, 0.f);
}

extern "C" void kernel_launch(void* const* d_in, const int* in_sizes, int n_in,
                              void* d_out, int out_size, void* d_ws, size_t ws_size,
                              hipStream_t stream) {
  const int N = in_sizes[0] / 24;
  const int E = in_sizes[1] / 2;
  const int G = out_size / 64;
  const int K = (N + BN - 1) >> BSH;
  const int ntiles = (E + TILE - 1) / TILE;

  fp x      = (fp)d_in[0];
  const int* edge  = (const int*)d_in[1];
  const int* batch = (const int*)d_in[2];
  fp w_in   = (fp)d_in[3];
  fp b_in   = (fp)d_in[4];
  fp w_l    = (fp)d_in[5];
  fp b_l    = (fp)d_in[6];
  fp w_r    = (fp)d_in[7];
  fp b_r    = (fp)d_in[8];
  fp att    = (fp)d_in[9];
  fp b_gat  = (fp)d_in[10];
  fp ln_g   = (fp)d_in[11];
  fp ln_b   = (fp)d_in[12];
  fp w_g1   = (fp)d_in[13];
  fp b_g1   = (fp)d_in[14];
  fp w_g2   = (fp)d_in[15];
  fp b_g2   = (fp)d_in[16];
  fp w_out  = (fp)d_in[17];
  fp b_out  = (fp)d_in[18];
  float* out = (float*)d_out;

  char* wp = (char*)d_ws;
  auto alloc = [&](size_t bytes) -> char* {
    char* p = wp; wp += (bytes + 255) & ~(size_t)255; return p;
  };
  float*    h       = (float*)   alloc((size_t)N*64*sizeof(float));
  unsigned* xl16    = (unsigned*)alloc((size_t)N*32*sizeof(unsigned));
  unsigned* xr16    = (unsigned*)alloc((size_t)N*32*sizeof(unsigned));
  int*      col     = (int*)     alloc((size_t)E*sizeof(int));
  unsigned* packed  = (unsigned*)alloc((size_t)E*sizeof(unsigned));
  int*      counts  = (int*)     alloc((size_t)K*ntiles*sizeof(int));
  int*      btotal  = (int*)     alloc((size_t)K*sizeof(int));
  int*      bbase   = (int*)     alloc((size_t)(K+1)*sizeof(int));
  int*      row_ptr = (int*)     alloc((size_t)(N+1)*sizeof(int));
  float*    gate    = (float*)   alloc((size_t)N*sizeof(float));
  float*    gmax    = (float*)   alloc((size_t)G*sizeof(float));
  float*    gsum    = (float*)   alloc((size_t)(G + G*64)*sizeof(float));
  float*    embsum  = gsum + G;

  const int* srcA = edge;
  const int* dstA = edge + E;

  k_in<<<(N + 3)/4, 256, 0, stream>>>(x, w_in, b_in, h, N);

  t_hist<<<ntiles, 256, 0, stream>>>(dstA, counts, E, K, ntiles);
  s_scan_tiles<<<K, 512, 0, stream>>>(counts, btotal, ntiles);
  s_scan_buckets<<<1, 512, 0, stream>>>(btotal, bbase, K, E);
  t_scatter<<<ntiles, 256, 0, stream>>>(srcA, dstA, counts, bbase, packed, E, K, ntiles);
  k_fine<<<K, 256, 0, stream>>>(packed, bbase, row_ptr, col, N, K);

  for (int i = 0; i < 3; ++i){
    k_xfm<<<(N + 63)/64, 256, 0, stream>>>(h, w_l + i*4096, b_l + i*64, w_r + i*4096, b_r + i*64,
                                           xl16, xr16, N);
    k_gat<<<(N + 3)/4, 256, 0, stream>>>(xl16, xr16, h, row_ptr, col,
                                         att + i*64, b_gat + i*64, ln_g + i*64, ln_b + i*64,
                                         N, i < 2 ? 1 : 0);
  }
  k_gate<<<(N + 15)/16, 256, 0, stream>>>(h, w_g1, b_g1, w_g2, b_g2, gate, N);
  k_gmax<<<G, 256, 0, stream>>>(gate, batch, gmax, gsum, embsum, N);
  k_emb<<<(N + 255)/256, 256, 0, stream>>>(h, gate, batch, gmax, gsum, embsum, N);
  k_out<<<G, 64, 0, stream>>>(embsum, gsum, w_out, b_out, out, G);
}